// Round 3
// baseline (272.065 us; speedup 1.0000x reference)
//
#include <hip/hip_runtime.h>
#include <hip/hip_bf16.h>

typedef __hip_bfloat16 bf16;
typedef __attribute__((ext_vector_type(8))) short bfrag8;   // 8 bf16 (MFMA A/B frag)
typedef __attribute__((ext_vector_type(8))) int intx8;      // 32 fp8 bytes (MX frag)
typedef __attribute__((ext_vector_type(4))) float floatx4;  // MFMA C/D frag

// Scale ladder (powers of 2, folded exactly in fp32 epilogues):
//   Wp8 = Wp*2^11 ; St8 = (exp(v)-1)*2^12 ; xs8 = (x/Z)*2^16
//   Dlt = acc5*2^-10 (= Delta*2^18) ; out = acc6*2^-29 + base[d]

__device__ __forceinline__ unsigned char f2fp8(float f) {
    f = fminf(fmaxf(f, -448.f), 448.f);            // clamp: overflow->NaN is the r5 killer
    return (unsigned char)(__builtin_amdgcn_cvt_pk_fp8_f32(f, f, 0, false) & 0xFF);
}

__device__ __forceinline__ void async_copy16(const void* g, void* lds) {
    __builtin_amdgcn_global_load_lds(
        (const __attribute__((address_space(1))) unsigned int*)g,
        (__attribute__((address_space(3))) unsigned int*)lds, 16, 0, 0);
}

// ---------------------------------------------------------------------------
// bf16 GEMM (PROVEN round-4 core): out[rowA][rowB] = sum_k A[rowA][k]*B[rowB][k]
// OUTKIND: 0 bf16, 1 f32, 2 fp8 of (exp-1)*4096 (with EXPZ).
// ---------------------------------------------------------------------------
template<int BIASMODE, int OUTKIND, bool EXPZ, bool MFAST>
__global__ __launch_bounds__(256)
void gemm128(const bf16* __restrict__ Ag, long sAb, int lda,
             const bf16* __restrict__ Bg, long sBb, int ldb,
             void* __restrict__ Cg, long sCb, int ldc,
             const float* __restrict__ scl, const float* __restrict__ b2,
             float* __restrict__ Zp, int K, int logfast)
{
    __shared__ unsigned short As[128 * 64];
    __shared__ unsigned short Bs[128 * 64];

    const int lin = blockIdx.x;
    const int bz  = lin & 7;              // XCD-aware: one batch per XCD
    const int s   = lin >> 3;
    const int msk = (1 << logfast) - 1;
    int mT, nT;
    if (MFAST) { mT = s & msk; nT = s >> logfast; }
    else       { nT = s & msk; mT = s >> logfast; }

    const bf16* A  = Ag + (size_t)bz * sAb + (size_t)mT * 128 * lda;
    const bf16* Bp = Bg + (size_t)bz * sBb + (size_t)nT * 128 * ldb;
    const int t = threadIdx.x, wave = t >> 6, lane = t & 63;
    const int qrow = lane & 15, quad = lane >> 4;
    const int wr = (wave >> 1) * 64, wc = (wave & 1) * 64;

    floatx4 acc[4][4] = {};

    for (int k0 = 0; k0 < K; k0 += 64) {
        #pragma unroll
        for (int j = 0; j < 4; ++j) {
            int c = j * 256 + t;
            int r = c >> 3, p = c & 7;
            int g = p ^ (r & 7);
            async_copy16(A + (size_t)r * lda + k0 + g * 8, &As[c * 8]);
        }
        #pragma unroll
        for (int j = 0; j < 4; ++j) {
            int c = j * 256 + t;
            int r = c >> 3, p = c & 7;
            int g = p ^ (r & 7);
            async_copy16(Bp + (size_t)r * ldb + k0 + g * 8, &Bs[c * 8]);
        }
        __syncthreads();

        #pragma unroll
        for (int ks = 0; ks < 2; ++ks) {
            bfrag8 af[4], bfv[4];
            #pragma unroll
            for (int mi = 0; mi < 4; ++mi) {
                int row = wr + mi * 16 + qrow;
                int ck  = ks * 4 + quad;
                af[mi] = *(const bfrag8*)&As[row * 64 + ((ck ^ (row & 7)) * 8)];
            }
            #pragma unroll
            for (int ni = 0; ni < 4; ++ni) {
                int row = wc + ni * 16 + qrow;
                int ck  = ks * 4 + quad;
                bfv[ni] = *(const bfrag8*)&Bs[row * 64 + ((ck ^ (row & 7)) * 8)];
            }
            #pragma unroll
            for (int mi = 0; mi < 4; ++mi)
                #pragma unroll
                for (int ni = 0; ni < 4; ++ni)
                    acc[mi][ni] = __builtin_amdgcn_mfma_f32_16x16x32_bf16(
                        af[mi], bfv[ni], acc[mi][ni], 0, 0, 0);
        }
        __syncthreads();
    }

    // D layout: col=lane&15, row=quad*4+reg  [m89-verified]
    const int bmr = mT * 128 + wr, bnc = nT * 128 + wc;
    float zp[4] = {0.f, 0.f, 0.f, 0.f};
    #pragma unroll
    for (int mi = 0; mi < 4; ++mi) {
        #pragma unroll
        for (int ni = 0; ni < 4; ++ni) {
            int col = bnc + ni * 16 + qrow;
            #pragma unroll
            for (int r = 0; r < 4; ++r) {
                int row = bmr + mi * 16 + quad * 4 + r;
                float v = acc[mi][ni][r];
                if (EXPZ) { float e = __expf(v); zp[ni] += e; v = (e - 1.0f) * 4096.0f; }
                if (BIASMODE == 1) v = v * scl[col] + b2[col];
                if (BIASMODE == 2) v += scl[row];
                if (OUTKIND == 1)
                    ((float*)Cg + (size_t)bz * sCb)[(size_t)row * ldc + col] = v;
                else if (OUTKIND == 0)
                    ((bf16*)Cg + (size_t)bz * sCb)[(size_t)row * ldc + col] = __float2bfloat16(v);
                else
                    ((unsigned char*)Cg + (size_t)bz * sCb)[(size_t)row * ldc + col] = f2fp8(v);
            }
        }
    }
    if (EXPZ) {
        #pragma unroll
        for (int ni = 0; ni < 4; ++ni) {
            float tt = zp[ni];
            tt += __shfl_xor(tt, 16, 64);
            tt += __shfl_xor(tt, 32, 64);
            if (quad == 0)
                atomicAdd(&Zp[bz * 2048 + bnc + ni * 16 + qrow], tt);
        }
    }
}

// ---------------------------------------------------------------------------
// fp8 MX GEMM (stages 5/6), ROUND 3: 256x256 tile, 256 threads (4 waves),
// wave tile 128x128 (2Mx2N wave grid), acc[8][8] (256 VGPR).
// Rationale: LDS-read-bound at 8 waves (192KB/tile > MFMA 2212cyc); 4-wave
// 128x128 wave tiles cut LDS reads to 128KB/tile (131 FLOP/B) ~= MFMA time.
// ONE barrier per K-tile (entry vmcnt(0)+s_barrier); no intra-tile barriers
// so waves drift and reads overlap MFMAs across waves.
// Race audit: reads of tile kt-1 are register-landed (MFMA-consumed) before
// any wave reaches the entry barrier of kt, so staging kt+1 into slot^1
// after that barrier cannot clobber in-flight reads.
// MODE 0: fp8 out, v=acc*os.  MODE 2: f32 out, v=acc*os + rowb[bz*1024+row].
// ---------------------------------------------------------------------------
template<int MODE, bool MFAST>
__global__ __launch_bounds__(256, 1)
void gemm_f8(const unsigned char* __restrict__ Ag, long sAb, int lda,
             const unsigned char* __restrict__ Bg, long sBb, int ldb,
             void* __restrict__ Cg, long sCb, int ldc,
             const float* __restrict__ rowb, float os, int K, int logfast)
{
    // As[slot] = smem + slot*32768 ; Bs[slot] = smem + 65536 + slot*32768
    __shared__ __align__(16) unsigned char smem[131072];

    const int lin = blockIdx.x;
    const int bz  = lin & 7;              // one batch per XCD
    const int s0  = lin >> 3;
    const int msk = (1 << logfast) - 1;
    int mT, nT;
    if (MFAST) { mT = s0 & msk; nT = s0 >> logfast; }
    else       { nT = s0 & msk; mT = s0 >> logfast; }

    const unsigned char* A  = Ag + (size_t)bz * sAb + (size_t)mT * 256 * lda;
    const unsigned char* Bp = Bg + (size_t)bz * sBb + (size_t)nT * 256 * ldb;
    const int t = threadIdx.x, wave = t >> 6, lane = t & 63;
    const int qrow = lane & 15, quad = lane >> 4;
    const int wm = (wave >> 1) * 128;     // wave row base (2 M-waves)
    const int wn = (wave & 1) * 128;      // wave col base (2 N-waves)

    floatx4 acc[8][8] = {};

    // stage one 256x128B K-tile of A and B into LDS slot (16 loads/thread).
    // swizzle: chunk g = p ^ (row&7); LDS dest stays linear (gload_lds rule).
    auto stage = [&](int kt, int slot) {
        const int k0 = kt << 7;
        unsigned char* Ad = &smem[slot * 32768];
        unsigned char* Bd = &smem[65536 + slot * 32768];
        #pragma unroll
        for (int j = 0; j < 8; ++j) {
            int c = j * 256 + t;
            int r = c >> 3, p = c & 7, g = p ^ (r & 7);
            async_copy16(A + (size_t)r * lda + k0 + g * 16, Ad + c * 16);
        }
        #pragma unroll
        for (int j = 0; j < 8; ++j) {
            int c = j * 256 + t;
            int r = c >> 3, p = c & 7, g = p ^ (r & 7);
            async_copy16(Bp + (size_t)r * ldb + k0 + g * 16, Bd + c * 16);
        }
    };

    const int NT = K >> 7;
    stage(0, 0);

    for (int kt = 0; kt < NT; ++kt) {
        const int slot = kt & 1;
        const unsigned char* As = &smem[slot * 32768];
        const unsigned char* Bs = &smem[65536 + slot * 32768];

        // entry: this tile's loads landed (per-wave vmcnt + all-waves barrier),
        // and every wave has finished reading slot^1 (consumed by MFMAs).
        asm volatile("s_waitcnt vmcnt(0)" ::: "memory");
        __builtin_amdgcn_sched_barrier(0);
        __builtin_amdgcn_s_barrier();
        __builtin_amdgcn_sched_barrier(0);

        if (kt + 1 < NT) stage(kt + 1, slot ^ 1);   // vmem-issue early; lands in slot^1

        intx8 bfr[8];
        #pragma unroll
        for (int ni = 0; ni < 8; ++ni) {
            int row = wn + ni * 16 + qrow, sw = row & 7;
            union { intx8 v; uint4 q[2]; } u;
            u.q[0] = *(const uint4*)&Bs[row * 128 + (((quad * 2    ) ^ sw) * 16)];
            u.q[1] = *(const uint4*)&Bs[row * 128 + (((quad * 2 + 1) ^ sw) * 16)];
            bfr[ni] = u.v;
        }
        #pragma unroll
        for (int mi = 0; mi < 8; ++mi) {
            int row = wm + mi * 16 + qrow, sw = row & 7;
            union { intx8 v; uint4 q[2]; } u;
            u.q[0] = *(const uint4*)&As[row * 128 + (((quad * 2    ) ^ sw) * 16)];
            u.q[1] = *(const uint4*)&As[row * 128 + (((quad * 2 + 1) ^ sw) * 16)];
            intx8 af = u.v;
            #pragma unroll
            for (int ni = 0; ni < 8; ++ni)
                acc[mi][ni] = __builtin_amdgcn_mfma_scale_f32_16x16x128_f8f6f4(
                    af, bfr[ni], acc[mi][ni], 0, 0, 0, 127, 0, 127); // fp8/fp8, scales 1.0
        }
    }

    // D layout: col=lane&15, row=quad*4+reg  [shape-determined, dtype-independent]
    const int bmr = mT * 256 + wm, bnc = nT * 256 + wn;
    #pragma unroll
    for (int mi = 0; mi < 8; ++mi) {
        int row0 = bmr + mi * 16 + quad * 4;
        float4 rb4;
        if (MODE == 2) rb4 = *(const float4*)&rowb[bz * 1024 + row0];
        #pragma unroll
        for (int ni = 0; ni < 8; ++ni) {
            int col = bnc + ni * 16 + qrow;
            floatx4 a = acc[mi][ni];
            if (MODE == 2) {
                float* Co = (float*)Cg + (size_t)bz * sCb;
                Co[(size_t)(row0 + 0) * ldc + col] = a[0] * os + rb4.x;
                Co[(size_t)(row0 + 1) * ldc + col] = a[1] * os + rb4.y;
                Co[(size_t)(row0 + 2) * ldc + col] = a[2] * os + rb4.z;
                Co[(size_t)(row0 + 3) * ldc + col] = a[3] * os + rb4.w;
            } else {
                unsigned char* C8 = (unsigned char*)Cg + (size_t)bz * sCb;
                #pragma unroll
                for (int r = 0; r < 4; ++r)
                    C8[(size_t)(row0 + r) * ldc + col] = f2fp8(a[r] * os);
            }
        }
    }
}

// Wk,Wq -> Wkqb bf16 (concat 256 rows); Wp -> Wp8 fp8 (*2^11). 8 elems/thread.
__global__ __launch_bounds__(256)
void conv_w(const float* __restrict__ Wk, const float* __restrict__ Wq,
            const float* __restrict__ Wp, bf16* __restrict__ Wkqb,
            unsigned char* __restrict__ Wp8)
{
    int i = blockIdx.x * 256 + threadIdx.x;   // 640 blocks
    if (i < 32768) {
        const float* src = (i < 16384) ? Wk : Wq;
        int off = (i < 16384) ? i : i - 16384;
        bf16* dst = Wkqb + (size_t)((i < 16384) ? 0 : 131072);
        const float4* sp = (const float4*)src + (size_t)off * 2;
        float4 a = sp[0], b = sp[1];
        union { uint4 u; unsigned short h[8]; } o;
        union { bf16 h; unsigned short u; } cv;
        cv.h = __float2bfloat16(a.x); o.h[0] = cv.u;
        cv.h = __float2bfloat16(a.y); o.h[1] = cv.u;
        cv.h = __float2bfloat16(a.z); o.h[2] = cv.u;
        cv.h = __float2bfloat16(a.w); o.h[3] = cv.u;
        cv.h = __float2bfloat16(b.x); o.h[4] = cv.u;
        cv.h = __float2bfloat16(b.y); o.h[5] = cv.u;
        cv.h = __float2bfloat16(b.z); o.h[6] = cv.u;
        cv.h = __float2bfloat16(b.w); o.h[7] = cv.u;
        ((uint4*)dst)[off] = o.u;
    } else {
        int off = i - 32768;   // Wp: 131072 chunks
        const float4* sp = (const float4*)Wp + (size_t)off * 2;
        float4 a = sp[0], b = sp[1];
        unsigned char o[8];
        o[0] = f2fp8(a.x * 2048.f); o[1] = f2fp8(a.y * 2048.f);
        o[2] = f2fp8(a.z * 2048.f); o[3] = f2fp8(a.w * 2048.f);
        o[4] = f2fp8(b.x * 2048.f); o[5] = f2fp8(b.y * 2048.f);
        o[6] = f2fp8(b.z * 2048.f); o[7] = f2fp8(b.w * 2048.f);
        uint2 w;
        w.x = (unsigned int)o[0] | ((unsigned int)o[1] << 8) | ((unsigned int)o[2] << 16) | ((unsigned int)o[3] << 24);
        w.y = (unsigned int)o[4] | ((unsigned int)o[5] << 8) | ((unsigned int)o[6] << 16) | ((unsigned int)o[7] << 24);
        ((uint2*)Wp8)[off] = w;
    }
}

// x fp32 [C,L] -> xt bf16 [L,C]  (round-4 proven transpose)
__global__ __launch_bounds__(256)
void conv_x(const float* __restrict__ x, bf16* __restrict__ xt)
{
    const int b = blockIdx.z;
    const int l0 = blockIdx.x * 64, c0 = blockIdx.y * 64;
    const float* xp = x + (size_t)b * 1024 * 2048;
    bf16* xtp = xt + (size_t)b * 2048 * 1024;
    __shared__ unsigned short tile[64][65];
    const int t = threadIdx.x, tr = t >> 4, tc4 = (t & 15) * 4;
    union { bf16 h; unsigned short u; } cv;
    #pragma unroll
    for (int i = 0; i < 4; ++i) {
        int r = i * 16 + tr;
        float4 v = *(const float4*)(xp + (size_t)(c0 + r) * 2048 + l0 + tc4);
        cv.h = __float2bfloat16(v.x); tile[r][tc4]     = cv.u;
        cv.h = __float2bfloat16(v.y); tile[r][tc4 + 1] = cv.u;
        cv.h = __float2bfloat16(v.z); tile[r][tc4 + 2] = cv.u;
        cv.h = __float2bfloat16(v.w); tile[r][tc4 + 3] = cv.u;
    }
    __syncthreads();
    #pragma unroll
    for (int i = 0; i < 4; ++i) {
        int lr = i * 16 + tr;
        union { uint2 u; unsigned short h[4]; } o;
        #pragma unroll
        for (int j = 0; j < 4; ++j) o.h[j] = tile[tc4 + j][lr];
        *(uint2*)(xtp + (size_t)(l0 + lr) * 1024 + c0 + tc4) = o.u;
    }
}

__global__ void prep_bias(const float* __restrict__ bk, const float* __restrict__ bq,
                          float* __restrict__ scl, float* __restrict__ b2, float kscale)
{
    int t = threadIdx.x;   // 256
    float s = (t < 128) ? kscale : 1.0f;
    scl[t] = s;
    b2[t] = ((t < 128) ? bk[t] : bq[t - 128]) * s;
}

// xs8[b][c][l] = fp8(x/Z * 2^16); colsum[b][c] = sum_l x/Z (exact fp32).
__global__ __launch_bounds__(256)
void normx(const float* __restrict__ x, const float* __restrict__ Z,
           unsigned char* __restrict__ xs, float* __restrict__ colsum)
{
    const int bc = blockIdx.x;            // b*1024 + c
    const int b  = bc >> 10;
    const int t  = threadIdx.x;
    const float* xp = x + (size_t)bc * 2048 + t * 8;
    const float* zp = Z + b * 2048 + t * 8;
    float4 a = ((const float4*)xp)[0], c4 = ((const float4*)xp)[1];
    float4 z0 = ((const float4*)zp)[0], z1 = ((const float4*)zp)[1];
    float v[8];
    v[0] = a.x  / fmaxf(z0.x, 1e-10f); v[1] = a.y / fmaxf(z0.y, 1e-10f);
    v[2] = a.z  / fmaxf(z0.z, 1e-10f); v[3] = a.w / fmaxf(z0.w, 1e-10f);
    v[4] = c4.x / fmaxf(z1.x, 1e-10f); v[5] = c4.y / fmaxf(z1.y, 1e-10f);
    v[6] = c4.z / fmaxf(z1.z, 1e-10f); v[7] = c4.w / fmaxf(z1.w, 1e-10f);
    float s = 0.f;
    unsigned char o[8];
    #pragma unroll
    for (int j = 0; j < 8; ++j) { s += v[j]; o[j] = f2fp8(v[j] * 65536.f); }
    uint2 w;
    w.x = (unsigned int)o[0] | ((unsigned int)o[1] << 8) | ((unsigned int)o[2] << 16) | ((unsigned int)o[3] << 24);
    w.y = (unsigned int)o[4] | ((unsigned int)o[5] << 8) | ((unsigned int)o[6] << 16) | ((unsigned int)o[7] << 24);
    ((uint2*)(xs + (size_t)bc * 2048))[t] = w;
    #pragma unroll
    for (int off = 32; off >= 1; off >>= 1) s += __shfl_xor(s, off, 64);
    __shared__ float red[4];
    if ((t & 63) == 0) red[t >> 6] = s;
    __syncthreads();
    if (t == 0) colsum[bc] = red[0] + red[1] + red[2] + red[3];
}

// base[b][d] = bp[d] + sum_c Wp[d,c]*colsum[b][c]  (exact fp32 path)
__global__ __launch_bounds__(256)
void basek(const float* __restrict__ Wp, const float* __restrict__ colsum,
           const float* __restrict__ bp, float* __restrict__ base)
{
    const int d = blockIdx.x, t = threadIdx.x;
    float4 w = *(const float4*)(Wp + (size_t)d * 1024 + t * 4);
    float pb[8];
    #pragma unroll
    for (int b = 0; b < 8; ++b) {
        float4 cs = *(const float4*)(colsum + b * 1024 + t * 4);
        pb[b] = w.x * cs.x + w.y * cs.y + w.z * cs.z + w.w * cs.w;
    }
    __shared__ float red[8][4];
    #pragma unroll
    for (int b = 0; b < 8; ++b) {
        float s = pb[b];
        #pragma unroll
        for (int off = 32; off >= 1; off >>= 1) s += __shfl_xor(s, off, 64);
        if ((t & 63) == 0) red[b][t >> 6] = s;
    }
    __syncthreads();
    if (t < 8) base[t * 1024 + d] = bp[d] + red[t][0] + red[t][1] + red[t][2] + red[t][3];
}

extern "C" void kernel_launch(void* const* d_in, const int* in_sizes, int n_in,
                              void* d_out, int out_size, void* d_ws, size_t ws_size,
                              hipStream_t stream)
{
    const float* x  = (const float*)d_in[0];
    const float* Wk = (const float*)d_in[1];
    const float* bk = (const float*)d_in[2];
    const float* Wq = (const float*)d_in[3];
    const float* bq = (const float*)d_in[4];
    const float* Wp = (const float*)d_in[5];
    const float* bp = (const float*)d_in[6];
    float* out = (float*)d_out;

    const float kscale = 2.0f / 2048.0f;

    // ws layout: xt bf16 33.5MB (Dlt fp8 16.8MB aliases) | KQt bf16 8.4MB |
    //            Wkqb bf16 0.5MB | Wp8 1MB | St8 33.5MB | xs8 16.8MB | floats
    bf16* xt   = (bf16*)d_ws;
    bf16* KQt  = xt + (size_t)8 * 2048 * 1024;
    bf16* Wkqb = KQt + (size_t)8 * 2048 * 256;
    unsigned char* Wp8 = (unsigned char*)(Wkqb + (size_t)256 * 1024);
    unsigned char* St8 = Wp8 + (size_t)1048576;              // [b][m][l]
    unsigned char* xs8 = St8 + (size_t)8 * 2048 * 2048;      // [b][c][l]
    float* Z      = (float*)(xs8 + (size_t)8 * 1024 * 2048); // [b][2048]
    float* colsum = Z + 8 * 2048;
    float* base   = colsum + 8 * 1024;
    float* scl    = base + 8 * 1024;
    float* b2     = scl + 256;
    unsigned char* Dlt = (unsigned char*)xt;                 // [b][m][c] aliases xt

    dim3 blk(256, 1, 1);

    prep_bias<<<dim3(1), blk, 0, stream>>>(bk, bq, scl, b2, kscale);
    conv_w<<<dim3(640), blk, 0, stream>>>(Wk, Wq, Wp, Wkqb, Wp8);
    conv_x<<<dim3(32, 16, 8), blk, 0, stream>>>(x, xt);

    // stage 1+2 (bf16, proven): KQt[l][0:128]=K*kscale, [128:256]=Q
    gemm128<1, 0, false, false><<<dim3(8 * 16 * 2), blk, 0, stream>>>(
        xt, 2048L * 1024, 1024,  Wkqb, 0, 1024,
        KQt, 2048L * 256, 256,  scl, b2, nullptr, 1024, 1);

    hipMemsetAsync(Z, 0, (size_t)8 * 2048 * sizeof(float), stream);

    // stage 3 (bf16 core, proven; fp8-d store): St8[m][l] = fp8((exp(v)-1)*2^12);
    // Z[l] += col sums of exp (exact fp32, pre-clamp).
    gemm128<0, 2, true, false><<<dim3(8 * 16 * 16), blk, 0, stream>>>(
        KQt + 128, 2048L * 256, 256,  KQt, 2048L * 256, 256,
        St8, 2048L * 2048, 2048,  nullptr, nullptr, Z, 128, 4);

    normx<<<dim3(8 * 1024), blk, 0, stream>>>(x, Z, xs8, colsum);
    basek<<<dim3(1024), blk, 0, stream>>>(Wp, colsum, bp, base);

    // stage 5 (fp8 MX, 256^2 4-wave): Dlt[m][c] = fp8(acc*2^-10)
    // grid: 8 XCD-batches x (mT 8 x nT 4) = 256 blocks = 1/CU
    gemm_f8<0, false><<<dim3(8 * 8 * 4), blk, 0, stream>>>(
        St8, 2048L * 2048, 2048,  xs8, 1024L * 2048, 2048,
        Dlt, 2048L * 1024, 1024,  nullptr, 0.0009765625f, 2048, 2);

    // stage 6 (fp8 MX, 256^2 4-wave): out[d][m] = acc*2^-29 + base[b][d]
    // grid: 8 x (mT 4 x nT 8) = 256 blocks = 1/CU
    gemm_f8<2, true><<<dim3(8 * 4 * 8), blk, 0, stream>>>(
        Wp8, 0, 1024,  Dlt, 2048L * 1024, 1024,
        out, 1024L * 2048, 2048,  base, 1.862645149230957e-9f, 1024, 2);
}

// Round 4
// 261.850 us; speedup vs baseline: 1.0390x; 1.0390x over previous
//
#include <hip/hip_runtime.h>
#include <hip/hip_bf16.h>

typedef __hip_bfloat16 bf16;
typedef __attribute__((ext_vector_type(8))) short bfrag8;   // 8 bf16 (MFMA A/B frag)
typedef __attribute__((ext_vector_type(8))) int intx8;      // 32 fp8 bytes (MX frag)
typedef __attribute__((ext_vector_type(4))) float floatx4;  // MFMA C/D frag

// Scale ladder (powers of 2, folded exactly in fp32 epilogues):
//   Wp8 = Wp*2^11 ; St8 = (exp(v)-1)*2^12 ; xs8 = (x/Z)*2^16
//   Dlt = acc5*2^-10 (= Delta*2^18) ; out = acc6*2^-29 + base[d]

__device__ __forceinline__ unsigned char f2fp8(float f) {
    f = fminf(fmaxf(f, -448.f), 448.f);            // clamp: overflow->NaN is the r5 killer
    return (unsigned char)(__builtin_amdgcn_cvt_pk_fp8_f32(f, f, 0, false) & 0xFF);
}

__device__ __forceinline__ void async_copy16(const void* g, void* lds) {
    __builtin_amdgcn_global_load_lds(
        (const __attribute__((address_space(1))) unsigned int*)g,
        (__attribute__((address_space(3))) unsigned int*)lds, 16, 0, 0);
}

// ---------------------------------------------------------------------------
// bf16 GEMM (PROVEN round-4 core): out[rowA][rowB] = sum_k A[rowA][k]*B[rowB][k]
// OUTKIND: 0 bf16, 1 f32, 2 fp8 of (exp-1)*4096 (with EXPZ).
// ---------------------------------------------------------------------------
template<int BIASMODE, int OUTKIND, bool EXPZ, bool MFAST>
__global__ __launch_bounds__(256)
void gemm128(const bf16* __restrict__ Ag, long sAb, int lda,
             const bf16* __restrict__ Bg, long sBb, int ldb,
             void* __restrict__ Cg, long sCb, int ldc,
             const float* __restrict__ scl, const float* __restrict__ b2,
             float* __restrict__ Zp, int K, int logfast)
{
    __shared__ unsigned short As[128 * 64];
    __shared__ unsigned short Bs[128 * 64];

    const int lin = blockIdx.x;
    const int bz  = lin & 7;              // XCD-aware: one batch per XCD
    const int s   = lin >> 3;
    const int msk = (1 << logfast) - 1;
    int mT, nT;
    if (MFAST) { mT = s & msk; nT = s >> logfast; }
    else       { nT = s & msk; mT = s >> logfast; }

    const bf16* A  = Ag + (size_t)bz * sAb + (size_t)mT * 128 * lda;
    const bf16* Bp = Bg + (size_t)bz * sBb + (size_t)nT * 128 * ldb;
    const int t = threadIdx.x, wave = t >> 6, lane = t & 63;
    const int qrow = lane & 15, quad = lane >> 4;
    const int wr = (wave >> 1) * 64, wc = (wave & 1) * 64;

    floatx4 acc[4][4] = {};

    for (int k0 = 0; k0 < K; k0 += 64) {
        #pragma unroll
        for (int j = 0; j < 4; ++j) {
            int c = j * 256 + t;
            int r = c >> 3, p = c & 7;
            int g = p ^ (r & 7);
            async_copy16(A + (size_t)r * lda + k0 + g * 8, &As[c * 8]);
        }
        #pragma unroll
        for (int j = 0; j < 4; ++j) {
            int c = j * 256 + t;
            int r = c >> 3, p = c & 7;
            int g = p ^ (r & 7);
            async_copy16(Bp + (size_t)r * ldb + k0 + g * 8, &Bs[c * 8]);
        }
        __syncthreads();

        #pragma unroll
        for (int ks = 0; ks < 2; ++ks) {
            bfrag8 af[4], bfv[4];
            #pragma unroll
            for (int mi = 0; mi < 4; ++mi) {
                int row = wr + mi * 16 + qrow;
                int ck  = ks * 4 + quad;
                af[mi] = *(const bfrag8*)&As[row * 64 + ((ck ^ (row & 7)) * 8)];
            }
            #pragma unroll
            for (int ni = 0; ni < 4; ++ni) {
                int row = wc + ni * 16 + qrow;
                int ck  = ks * 4 + quad;
                bfv[ni] = *(const bfrag8*)&Bs[row * 64 + ((ck ^ (row & 7)) * 8)];
            }
            #pragma unroll
            for (int mi = 0; mi < 4; ++mi)
                #pragma unroll
                for (int ni = 0; ni < 4; ++ni)
                    acc[mi][ni] = __builtin_amdgcn_mfma_f32_16x16x32_bf16(
                        af[mi], bfv[ni], acc[mi][ni], 0, 0, 0);
        }
        __syncthreads();
    }

    // D layout: col=lane&15, row=quad*4+reg  [m89-verified]
    const int bmr = mT * 128 + wr, bnc = nT * 128 + wc;
    float zp[4] = {0.f, 0.f, 0.f, 0.f};
    #pragma unroll
    for (int mi = 0; mi < 4; ++mi) {
        #pragma unroll
        for (int ni = 0; ni < 4; ++ni) {
            int col = bnc + ni * 16 + qrow;
            #pragma unroll
            for (int r = 0; r < 4; ++r) {
                int row = bmr + mi * 16 + quad * 4 + r;
                float v = acc[mi][ni][r];
                if (EXPZ) { float e = __expf(v); zp[ni] += e; v = (e - 1.0f) * 4096.0f; }
                if (BIASMODE == 1) v = v * scl[col] + b2[col];
                if (BIASMODE == 2) v += scl[row];
                if (OUTKIND == 1)
                    ((float*)Cg + (size_t)bz * sCb)[(size_t)row * ldc + col] = v;
                else if (OUTKIND == 0)
                    ((bf16*)Cg + (size_t)bz * sCb)[(size_t)row * ldc + col] = __float2bfloat16(v);
                else
                    ((unsigned char*)Cg + (size_t)bz * sCb)[(size_t)row * ldc + col] = f2fp8(v);
            }
        }
    }
    if (EXPZ) {
        #pragma unroll
        for (int ni = 0; ni < 4; ++ni) {
            float tt = zp[ni];
            tt += __shfl_xor(tt, 16, 64);
            tt += __shfl_xor(tt, 32, 64);
            if (quad == 0)
                atomicAdd(&Zp[bz * 2048 + bnc + ni * 16 + qrow], tt);
        }
    }
}

// ---------------------------------------------------------------------------
// Stage-3 dedicated kernel: St8 = fp8((exp(S)-1)*4096), Z += colsum(exp(S)).
// S[m][l] = sum_k Q[m][k]*K[l][k], K=128 (single LDS shot, no dbuf).
// 256x256 tile, 512 threads (8 waves, 2Mx4N), 128KiB LDS, 2 barriers total.
// Swizzle: 16-byte chunks, phys = (ck&8)|((ck&7)^(row&7)); bank =
// ((ck&7)^(row&7))*4 -> bijective per 8-lane group -> conflict-free.
// ---------------------------------------------------------------------------
__global__ __launch_bounds__(512, 2)
void gemm_s3(const bf16* __restrict__ Ag, long sAb, int lda,
             const bf16* __restrict__ Bg, long sBb, int ldb,
             unsigned char* __restrict__ Cg, long sCb, int ldc,
             float* __restrict__ Zp)
{
    __shared__ __align__(16) unsigned char smem[131072];   // As 64KB | Bs 64KB

    const int lin = blockIdx.x;
    const int bz  = lin & 7;              // one batch per XCD (KQt batch = 1MB, L2-resident)
    const int s0  = lin >> 3;             // 0..63
    const int nT  = s0 & 7, mT = s0 >> 3;

    const bf16* A  = Ag + (size_t)bz * sAb + (size_t)mT * 256 * lda;
    const bf16* Bp = Bg + (size_t)bz * sBb + (size_t)nT * 256 * ldb;
    const int t = threadIdx.x, wave = t >> 6, lane = t & 63;
    const int qrow = lane & 15, quad = lane >> 4;
    const int wm = (wave >> 2) * 128;     // 2 M-waves
    const int wn = (wave & 3) * 64;       // 4 N-waves

    unsigned char* As = smem;
    unsigned char* Bs = smem + 65536;

    // stage the full 256x128-elem (256B/row) A and B panels; 16 loads/thread
    #pragma unroll
    for (int j = 0; j < 8; ++j) {
        int c = j * 512 + t;
        int r = c >> 4, p = c & 15;
        int g = (p & 8) | ((p & 7) ^ (r & 7));
        async_copy16(A + (size_t)r * lda + g * 8, As + c * 16);
    }
    #pragma unroll
    for (int j = 0; j < 8; ++j) {
        int c = j * 512 + t;
        int r = c >> 4, p = c & 15;
        int g = (p & 8) | ((p & 7) ^ (r & 7));
        async_copy16(Bp + (size_t)r * ldb + g * 8, Bs + c * 16);
    }
    asm volatile("s_waitcnt vmcnt(0)" ::: "memory");
    __builtin_amdgcn_s_barrier();

    floatx4 acc[8][4] = {};
    #pragma unroll
    for (int ks = 0; ks < 4; ++ks) {
        const int ck = ks * 4 + quad;     // 16B k-chunk index, 0..15
        bfrag8 bfv[4];
        #pragma unroll
        for (int ni = 0; ni < 4; ++ni) {
            int row = wn + ni * 16 + qrow;
            int ph  = (ck & 8) | ((ck & 7) ^ (row & 7));
            bfv[ni] = *(const bfrag8*)&Bs[row * 256 + ph * 16];
        }
        #pragma unroll
        for (int mi = 0; mi < 8; ++mi) {
            int row = wm + mi * 16 + qrow;
            int ph  = (ck & 8) | ((ck & 7) ^ (row & 7));
            bfrag8 af = *(const bfrag8*)&As[row * 256 + ph * 16];
            #pragma unroll
            for (int ni = 0; ni < 4; ++ni)
                acc[mi][ni] = __builtin_amdgcn_mfma_f32_16x16x32_bf16(
                    af, bfv[ni], acc[mi][ni], 0, 0, 0);
        }
    }

    // D layout: col=lane&15, row=quad*4+reg  [m89-verified]
    const int bmr = mT * 256 + wm, bnc = nT * 256 + wn;
    unsigned char* C8 = Cg + (size_t)bz * sCb;
    float zp[4] = {0.f, 0.f, 0.f, 0.f};
    #pragma unroll
    for (int mi = 0; mi < 8; ++mi) {
        #pragma unroll
        for (int ni = 0; ni < 4; ++ni) {
            int col = bnc + ni * 16 + qrow;
            #pragma unroll
            for (int r = 0; r < 4; ++r) {
                int row = bmr + mi * 16 + quad * 4 + r;
                float e = __expf(acc[mi][ni][r]);
                zp[ni] += e;
                C8[(size_t)row * ldc + col] = f2fp8((e - 1.0f) * 4096.0f);
            }
        }
    }
    #pragma unroll
    for (int ni = 0; ni < 4; ++ni) {
        float tt = zp[ni];
        tt += __shfl_xor(tt, 16, 64);
        tt += __shfl_xor(tt, 32, 64);
        if (quad == 0)
            atomicAdd(&Zp[bz * 2048 + bnc + ni * 16 + qrow], tt);
    }
}

// ---------------------------------------------------------------------------
// fp8 MX GEMM (stages 5/6): 256x256 tile, 512 threads (8 waves, 2Mx4N),
// BK=128 bytes, 8-phase schedule (round-2 best variant).
// MODE 0: fp8 out, v=acc*os.  MODE 2: f32 out, v=acc*os + rowb[bz*1024+row].
// ---------------------------------------------------------------------------
template<int MODE, bool MFAST>
__global__ __launch_bounds__(512, 2)
void gemm_f8(const unsigned char* __restrict__ Ag, long sAb, int lda,
             const unsigned char* __restrict__ Bg, long sBb, int ldb,
             void* __restrict__ Cg, long sCb, int ldc,
             const float* __restrict__ rowb, float os, int K, int logfast)
{
    // As[slot] = smem + slot*32768 ; Bs[slot] = smem + 65536 + slot*32768
    __shared__ __align__(16) unsigned char smem[131072];

    const int lin = blockIdx.x;
    const int bz  = lin & 7;              // one batch per XCD
    const int s0  = lin >> 3;
    const int msk = (1 << logfast) - 1;
    int mT, nT;
    if (MFAST) { mT = s0 & msk; nT = s0 >> logfast; }
    else       { nT = s0 & msk; mT = s0 >> logfast; }

    const unsigned char* A  = Ag + (size_t)bz * sAb + (size_t)mT * 256 * lda;
    const unsigned char* Bp = Bg + (size_t)bz * sBb + (size_t)nT * 256 * ldb;
    const int t = threadIdx.x, wave = t >> 6, lane = t & 63;
    const int qrow = lane & 15, quad = lane >> 4;
    const int wm = (wave >> 2) * 128;     // wave row base (2 M-waves)
    const int wn = (wave & 3) * 64;       // wave col base (4 N-waves)

    floatx4 acc[8][4] = {};

    // issue 4 of the 8 per-thread loads for tile kt into slot (part = 0 or 1).
    auto stage_part = [&](int kt, int slot, int part) {
        const int k0 = kt << 7;
        unsigned char* Ad = &smem[slot * 32768];
        unsigned char* Bd = &smem[65536 + slot * 32768];
        #pragma unroll
        for (int j = 0; j < 2; ++j) {
            int c = (part * 2 + j) * 512 + t;
            int r = c >> 3, p = c & 7, g = p ^ (r & 7);
            async_copy16(A + (size_t)r * lda + k0 + g * 16, Ad + c * 16);
        }
        #pragma unroll
        for (int j = 0; j < 2; ++j) {
            int c = (part * 2 + j) * 512 + t;
            int r = c >> 3, p = c & 7, g = p ^ (r & 7);
            async_copy16(Bp + (size_t)r * ldb + k0 + g * 16, Bd + c * 16);
        }
    };

    const int NT = K >> 7;
    stage_part(0, 0, 0);
    stage_part(0, 0, 1);

    for (int kt = 0; kt < NT; ++kt) {
        const int slot = kt & 1;
        const unsigned char* As = &smem[slot * 32768];
        const unsigned char* Bs = &smem[65536 + slot * 32768];

        // entry: tile kt's loads (issued during phases 0-1 of kt-1) landed.
        asm volatile("s_waitcnt vmcnt(0)" ::: "memory");
        __builtin_amdgcn_sched_barrier(0);
        __builtin_amdgcn_s_barrier();
        __builtin_amdgcn_sched_barrier(0);

        intx8 bfr[4];
        #pragma unroll
        for (int ph = 0; ph < 4; ++ph) {
            // ---- ds-read this phase's register subtile ----
            if (ph == 0) {
                #pragma unroll
                for (int ni = 0; ni < 4; ++ni) {
                    int row = wn + ni * 16 + qrow, sw = row & 7;
                    union { intx8 v; uint4 q[2]; } u;
                    u.q[0] = *(const uint4*)&Bs[row * 128 + (((quad * 2    ) ^ sw) * 16)];
                    u.q[1] = *(const uint4*)&Bs[row * 128 + (((quad * 2 + 1) ^ sw) * 16)];
                    bfr[ni] = u.v;
                }
            }
            intx8 af0, af1;
            {
                int row = wm + (2 * ph) * 16 + qrow, sw = row & 7;
                union { intx8 v; uint4 q[2]; } u;
                u.q[0] = *(const uint4*)&As[row * 128 + (((quad * 2    ) ^ sw) * 16)];
                u.q[1] = *(const uint4*)&As[row * 128 + (((quad * 2 + 1) ^ sw) * 16)];
                af0 = u.v;
            }
            {
                int row = wm + (2 * ph + 1) * 16 + qrow, sw = row & 7;
                union { intx8 v; uint4 q[2]; } u;
                u.q[0] = *(const uint4*)&As[row * 128 + (((quad * 2    ) ^ sw) * 16)];
                u.q[1] = *(const uint4*)&As[row * 128 + (((quad * 2 + 1) ^ sw) * 16)];
                af1 = u.v;
            }
            // ---- stage next tile's loads early (phases 0-1) ----
            if (ph < 2 && kt + 1 < NT) stage_part(kt + 1, slot ^ 1, ph);

            __builtin_amdgcn_sched_barrier(0);
            __builtin_amdgcn_s_barrier();
            asm volatile("s_waitcnt lgkmcnt(0)" ::: "memory");
            __builtin_amdgcn_sched_barrier(0);

            __builtin_amdgcn_s_setprio(1);
            #pragma unroll
            for (int ni = 0; ni < 4; ++ni)
                acc[2 * ph][ni] = __builtin_amdgcn_mfma_scale_f32_16x16x128_f8f6f4(
                    af0, bfr[ni], acc[2 * ph][ni], 0, 0, 0, 127, 0, 127);
            #pragma unroll
            for (int ni = 0; ni < 4; ++ni)
                acc[2 * ph + 1][ni] = __builtin_amdgcn_mfma_scale_f32_16x16x128_f8f6f4(
                    af1, bfr[ni], acc[2 * ph + 1][ni], 0, 0, 0, 127, 0, 127);
            __builtin_amdgcn_s_setprio(0);

            __builtin_amdgcn_sched_barrier(0);
            __builtin_amdgcn_s_barrier();
            __builtin_amdgcn_sched_barrier(0);
        }
    }

    // D layout: col=lane&15, row=quad*4+reg  [shape-determined, dtype-independent]
    const int bmr = mT * 256 + wm, bnc = nT * 256 + wn;
    #pragma unroll
    for (int mi = 0; mi < 8; ++mi) {
        int row0 = bmr + mi * 16 + quad * 4;
        float4 rb4;
        if (MODE == 2) rb4 = *(const float4*)&rowb[bz * 1024 + row0];
        #pragma unroll
        for (int ni = 0; ni < 4; ++ni) {
            int col = bnc + ni * 16 + qrow;
            floatx4 a = acc[mi][ni];
            if (MODE == 2) {
                float* Co = (float*)Cg + (size_t)bz * sCb;
                Co[(size_t)(row0 + 0) * ldc + col] = a[0] * os + rb4.x;
                Co[(size_t)(row0 + 1) * ldc + col] = a[1] * os + rb4.y;
                Co[(size_t)(row0 + 2) * ldc + col] = a[2] * os + rb4.z;
                Co[(size_t)(row0 + 3) * ldc + col] = a[3] * os + rb4.w;
            } else {
                unsigned char* C8 = (unsigned char*)Cg + (size_t)bz * sCb;
                #pragma unroll
                for (int r = 0; r < 4; ++r)
                    C8[(size_t)(row0 + r) * ldc + col] = f2fp8(a[r] * os);
            }
        }
    }
}

// Wk,Wq -> Wkqb bf16 (concat 256 rows); Wp -> Wp8 fp8 (*2^11). 8 elems/thread.
__global__ __launch_bounds__(256)
void conv_w(const float* __restrict__ Wk, const float* __restrict__ Wq,
            const float* __restrict__ Wp, bf16* __restrict__ Wkqb,
            unsigned char* __restrict__ Wp8)
{
    int i = blockIdx.x * 256 + threadIdx.x;   // 640 blocks
    if (i < 32768) {
        const float* src = (i < 16384) ? Wk : Wq;
        int off = (i < 16384) ? i : i - 16384;
        bf16* dst = Wkqb + (size_t)((i < 16384) ? 0 : 131072);
        const float4* sp = (const float4*)src + (size_t)off * 2;
        float4 a = sp[0], b = sp[1];
        union { uint4 u; unsigned short h[8]; } o;
        union { bf16 h; unsigned short u; } cv;
        cv.h = __float2bfloat16(a.x); o.h[0] = cv.u;
        cv.h = __float2bfloat16(a.y); o.h[1] = cv.u;
        cv.h = __float2bfloat16(a.z); o.h[2] = cv.u;
        cv.h = __float2bfloat16(a.w); o.h[3] = cv.u;
        cv.h = __float2bfloat16(b.x); o.h[4] = cv.u;
        cv.h = __float2bfloat16(b.y); o.h[5] = cv.u;
        cv.h = __float2bfloat16(b.z); o.h[6] = cv.u;
        cv.h = __float2bfloat16(b.w); o.h[7] = cv.u;
        ((uint4*)dst)[off] = o.u;
    } else {
        int off = i - 32768;   // Wp: 131072 chunks
        const float4* sp = (const float4*)Wp + (size_t)off * 2;
        float4 a = sp[0], b = sp[1];
        unsigned char o[8];
        o[0] = f2fp8(a.x * 2048.f); o[1] = f2fp8(a.y * 2048.f);
        o[2] = f2fp8(a.z * 2048.f); o[3] = f2fp8(a.w * 2048.f);
        o[4] = f2fp8(b.x * 2048.f); o[5] = f2fp8(b.y * 2048.f);
        o[6] = f2fp8(b.z * 2048.f); o[7] = f2fp8(b.w * 2048.f);
        uint2 w;
        w.x = (unsigned int)o[0] | ((unsigned int)o[1] << 8) | ((unsigned int)o[2] << 16) | ((unsigned int)o[3] << 24);
        w.y = (unsigned int)o[4] | ((unsigned int)o[5] << 8) | ((unsigned int)o[6] << 16) | ((unsigned int)o[7] << 24);
        ((uint2*)Wp8)[off] = w;
    }
}

// x fp32 [C,L] -> xt bf16 [L,C]  (round-4 proven transpose)
__global__ __launch_bounds__(256)
void conv_x(const float* __restrict__ x, bf16* __restrict__ xt)
{
    const int b = blockIdx.z;
    const int l0 = blockIdx.x * 64, c0 = blockIdx.y * 64;
    const float* xp = x + (size_t)b * 1024 * 2048;
    bf16* xtp = xt + (size_t)b * 2048 * 1024;
    __shared__ unsigned short tile[64][65];
    const int t = threadIdx.x, tr = t >> 4, tc4 = (t & 15) * 4;
    union { bf16 h; unsigned short u; } cv;
    #pragma unroll
    for (int i = 0; i < 4; ++i) {
        int r = i * 16 + tr;
        float4 v = *(const float4*)(xp + (size_t)(c0 + r) * 2048 + l0 + tc4);
        cv.h = __float2bfloat16(v.x); tile[r][tc4]     = cv.u;
        cv.h = __float2bfloat16(v.y); tile[r][tc4 + 1] = cv.u;
        cv.h = __float2bfloat16(v.z); tile[r][tc4 + 2] = cv.u;
        cv.h = __float2bfloat16(v.w); tile[r][tc4 + 3] = cv.u;
    }
    __syncthreads();
    #pragma unroll
    for (int i = 0; i < 4; ++i) {
        int lr = i * 16 + tr;
        union { uint2 u; unsigned short h[4]; } o;
        #pragma unroll
        for (int j = 0; j < 4; ++j) o.h[j] = tile[tc4 + j][lr];
        *(uint2*)(xtp + (size_t)(l0 + lr) * 1024 + c0 + tc4) = o.u;
    }
}

__global__ void prep_bias(const float* __restrict__ bk, const float* __restrict__ bq,
                          float* __restrict__ scl, float* __restrict__ b2, float kscale)
{
    int t = threadIdx.x;   // 256
    float s = (t < 128) ? kscale : 1.0f;
    scl[t] = s;
    b2[t] = ((t < 128) ? bk[t] : bq[t - 128]) * s;
}

// xs8[b][c][l] = fp8(x/Z * 2^16); colsum[b][c] = sum_l x/Z (exact fp32).
__global__ __launch_bounds__(256)
void normx(const float* __restrict__ x, const float* __restrict__ Z,
           unsigned char* __restrict__ xs, float* __restrict__ colsum)
{
    const int bc = blockIdx.x;            // b*1024 + c
    const int b  = bc >> 10;
    const int t  = threadIdx.x;
    const float* xp = x + (size_t)bc * 2048 + t * 8;
    const float* zp = Z + b * 2048 + t * 8;
    float4 a = ((const float4*)xp)[0], c4 = ((const float4*)xp)[1];
    float4 z0 = ((const float4*)zp)[0], z1 = ((const float4*)zp)[1];
    float v[8];
    v[0] = a.x  / fmaxf(z0.x, 1e-10f); v[1] = a.y / fmaxf(z0.y, 1e-10f);
    v[2] = a.z  / fmaxf(z0.z, 1e-10f); v[3] = a.w / fmaxf(z0.w, 1e-10f);
    v[4] = c4.x / fmaxf(z1.x, 1e-10f); v[5] = c4.y / fmaxf(z1.y, 1e-10f);
    v[6] = c4.z / fmaxf(z1.z, 1e-10f); v[7] = c4.w / fmaxf(z1.w, 1e-10f);
    float s = 0.f;
    unsigned char o[8];
    #pragma unroll
    for (int j = 0; j < 8; ++j) { s += v[j]; o[j] = f2fp8(v[j] * 65536.f); }
    uint2 w;
    w.x = (unsigned int)o[0] | ((unsigned int)o[1] << 8) | ((unsigned int)o[2] << 16) | ((unsigned int)o[3] << 24);
    w.y = (unsigned int)o[4] | ((unsigned int)o[5] << 8) | ((unsigned int)o[6] << 16) | ((unsigned int)o[7] << 24);
    ((uint2*)(xs + (size_t)bc * 2048))[t] = w;
    #pragma unroll
    for (int off = 32; off >= 1; off >>= 1) s += __shfl_xor(s, off, 64);
    __shared__ float red[4];
    if ((t & 63) == 0) red[t >> 6] = s;
    __syncthreads();
    if (t == 0) colsum[bc] = red[0] + red[1] + red[2] + red[3];
}

// base[b][d] = bp[d] + sum_c Wp[d,c]*colsum[b][c]  (exact fp32 path)
__global__ __launch_bounds__(256)
void basek(const float* __restrict__ Wp, const float* __restrict__ colsum,
           const float* __restrict__ bp, float* __restrict__ base)
{
    const int d = blockIdx.x, t = threadIdx.x;
    float4 w = *(const float4*)(Wp + (size_t)d * 1024 + t * 4);
    float pb[8];
    #pragma unroll
    for (int b = 0; b < 8; ++b) {
        float4 cs = *(const float4*)(colsum + b * 1024 + t * 4);
        pb[b] = w.x * cs.x + w.y * cs.y + w.z * cs.z + w.w * cs.w;
    }
    __shared__ float red[8][4];
    #pragma unroll
    for (int b = 0; b < 8; ++b) {
        float s = pb[b];
        #pragma unroll
        for (int off = 32; off >= 1; off >>= 1) s += __shfl_xor(s, off, 64);
        if ((t & 63) == 0) red[b][t >> 6] = s;
    }
    __syncthreads();
    if (t < 8) base[t * 1024 + d] = bp[d] + red[t][0] + red[t][1] + red[t][2] + red[t][3];
}

extern "C" void kernel_launch(void* const* d_in, const int* in_sizes, int n_in,
                              void* d_out, int out_size, void* d_ws, size_t ws_size,
                              hipStream_t stream)
{
    const float* x  = (const float*)d_in[0];
    const float* Wk = (const float*)d_in[1];
    const float* bk = (const float*)d_in[2];
    const float* Wq = (const float*)d_in[3];
    const float* bq = (const float*)d_in[4];
    const float* Wp = (const float*)d_in[5];
    const float* bp = (const float*)d_in[6];
    float* out = (float*)d_out;

    const float kscale = 2.0f / 2048.0f;

    // ws layout: xt bf16 33.5MB (Dlt fp8 16.8MB aliases) | KQt bf16 8.4MB |
    //            Wkqb bf16 0.5MB | Wp8 1MB | St8 33.5MB | xs8 16.8MB | floats
    bf16* xt   = (bf16*)d_ws;
    bf16* KQt  = xt + (size_t)8 * 2048 * 1024;
    bf16* Wkqb = KQt + (size_t)8 * 2048 * 256;
    unsigned char* Wp8 = (unsigned char*)(Wkqb + (size_t)256 * 1024);
    unsigned char* St8 = Wp8 + (size_t)1048576;              // [b][m][l]
    unsigned char* xs8 = St8 + (size_t)8 * 2048 * 2048;      // [b][c][l]
    float* Z      = (float*)(xs8 + (size_t)8 * 1024 * 2048); // [b][2048]
    float* colsum = Z + 8 * 2048;
    float* base   = colsum + 8 * 1024;
    float* scl    = base + 8 * 1024;
    float* b2     = scl + 256;
    unsigned char* Dlt = (unsigned char*)xt;                 // [b][m][c] aliases xt

    dim3 blk(256, 1, 1);
    dim3 blk512(512, 1, 1);

    prep_bias<<<dim3(1), blk, 0, stream>>>(bk, bq, scl, b2, kscale);
    conv_w<<<dim3(640), blk, 0, stream>>>(Wk, Wq, Wp, Wkqb, Wp8);
    conv_x<<<dim3(32, 16, 8), blk, 0, stream>>>(x, xt);

    // stage 1+2 (bf16, proven): KQt[l][0:128]=K*kscale, [128:256]=Q
    gemm128<1, 0, false, false><<<dim3(8 * 16 * 2), blk, 0, stream>>>(
        xt, 2048L * 1024, 1024,  Wkqb, 0, 1024,
        KQt, 2048L * 256, 256,  scl, b2, nullptr, 1024, 1);

    hipMemsetAsync(Z, 0, (size_t)8 * 2048 * sizeof(float), stream);

    // stage 3 (NEW dedicated 256^2 single-shot kernel): St8[m][l] =
    // fp8((exp(v)-1)*2^12); Z[l] += col sums of exp (exact fp32).
    // grid: 8 batches x (mT 8 x nT 8) = 512 blocks
    gemm_s3<<<dim3(8 * 8 * 8), blk512, 0, stream>>>(
        KQt + 128, 2048L * 256, 256,  KQt, 2048L * 256, 256,
        St8, 2048L * 2048, 2048,  Z);

    normx<<<dim3(8 * 1024), blk, 0, stream>>>(x, Z, xs8, colsum);
    basek<<<dim3(1024), blk, 0, stream>>>(Wp, colsum, bp, base);

    // stage 5 (fp8 MX, 256^2 8-phase): Dlt[m][c] = fp8(acc*2^-10)
    // grid: 8 XCD-batches x (mT 8 x nT 4) = 256 blocks = 1/CU
    gemm_f8<0, false><<<dim3(8 * 8 * 4), blk512, 0, stream>>>(
        St8, 2048L * 2048, 2048,  xs8, 1024L * 2048, 2048,
        Dlt, 2048L * 1024, 1024,  nullptr, 0.0009765625f, 2048, 2);

    // stage 6 (fp8 MX, 256^2 8-phase): out[d][m] = acc*2^-29 + base[b][d]
    // grid: 8 x (mT 4 x nT 8) = 256 blocks = 1/CU
    gemm_f8<2, true><<<dim3(8 * 4 * 8), blk512, 0, stream>>>(
        Wp8, 0, 1024,  Dlt, 2048L * 1024, 1024,
        out, 1024L * 2048, 2048,  base, 1.862645149230957e-9f, 1024, 2);
}

// Round 5
// 245.368 us; speedup vs baseline: 1.1088x; 1.0672x over previous
//
#include <hip/hip_runtime.h>
#include <hip/hip_bf16.h>

typedef __hip_bfloat16 bf16;
typedef __attribute__((ext_vector_type(8))) short bfrag8;   // 8 bf16 (MFMA A/B frag)
typedef __attribute__((ext_vector_type(8))) int intx8;      // 32 fp8 bytes (MX frag)
typedef __attribute__((ext_vector_type(4))) float floatx4;  // MFMA C/D frag

// Scale ladder (powers of 2, folded exactly in fp32 epilogues):
//   Wp8 = Wp*2^11 ; St8 = (exp(v)-1)*2^12 ; xs8 = (x/Z)*2^16
//   Dlt = acc5*2^-10 (= Delta*2^18) ; out = acc6*2^-29 + base[d]

__device__ __forceinline__ unsigned char f2fp8(float f) {
    f = fminf(fmaxf(f, -448.f), 448.f);            // clamp: overflow->NaN is the r5 killer
    return (unsigned char)(__builtin_amdgcn_cvt_pk_fp8_f32(f, f, 0, false) & 0xFF);
}

__device__ __forceinline__ void async_copy16(const void* g, void* lds) {
    __builtin_amdgcn_global_load_lds(
        (const __attribute__((address_space(1))) unsigned int*)g,
        (__attribute__((address_space(3))) unsigned int*)lds, 16, 0, 0);
}

// ---------------------------------------------------------------------------
// Stage 1+2 FUSED with the x transpose (replaces conv_x + gemm128):
// KQt[l][a] = (sum_c bf16(x[c][l]) * Wkqb[a][c]) * scl[a] + b2[a]
// Tile: 64 l (M) x 256 a (N, full) per block; grid 8 bz x 32 mT = 256 blocks.
// x read ONCE (67MB) vs old path's 167MB (x->xt write + xt read x2).
// Xs staged raw [64c][64l] f32 via gload_lds (rows contiguous, no transpose);
// transpose happens at frag-read: 8 x ds_read_b32 stride-256B + cvt bf16
// (4-way bank conflict = 1.58x, m136 - acceptable). W path = proven swizzle.
// Numerics BIT-IDENTICAL to old path: same bf16 cvt per element, same
// ck=ks*4+quad accumulation order, same epilogue.
// ---------------------------------------------------------------------------
__global__ __launch_bounds__(256)
void gemm12(const float* __restrict__ xg, const bf16* __restrict__ Wkqb,
            bf16* __restrict__ KQt, const float* __restrict__ scl,
            const float* __restrict__ b2)
{
    __shared__ __align__(16) float Xs[64 * 64];            // [c][l] 16KB, linear
    __shared__ __align__(16) unsigned short Ws[256 * 64];  // [a][c] 32KB, swizzled

    const int lin = blockIdx.x;
    const int bz  = lin & 7;              // one batch per XCD
    const int mT  = lin >> 3;             // 0..31
    const int l0  = mT * 64;
    const float* xp = xg + (size_t)bz * 1024 * 2048;

    const int t = threadIdx.x, wave = t >> 6, lane = t & 63;
    const int qrow = lane & 15, quad = lane >> 4;
    const int wr = (wave >> 1) * 32, wc = (wave & 1) * 128;

    floatx4 acc[2][8] = {};

    for (int k0 = 0; k0 < 1024; k0 += 64) {
        // stage Xs: 64 c-rows x 64 l f32 (1024 16B-chunks, 4/thread), linear
        #pragma unroll
        for (int j = 0; j < 4; ++j) {
            int ci = j * 256 + t;
            int r = ci >> 4, li = (ci & 15) * 4;
            async_copy16(xp + (size_t)(k0 + r) * 2048 + l0 + li, &Xs[ci * 4]);
        }
        // stage Ws: 256 a-rows x 64 c bf16 (2048 chunks, 8/thread), swizzled
        #pragma unroll
        for (int j = 0; j < 8; ++j) {
            int ci = j * 256 + t;
            int r = ci >> 3, p = ci & 7, g = p ^ (r & 7);
            async_copy16(Wkqb + (size_t)r * 1024 + k0 + g * 8, &Ws[ci * 8]);
        }
        asm volatile("s_waitcnt vmcnt(0)" ::: "memory");
        __syncthreads();

        #pragma unroll
        for (int ks = 0; ks < 2; ++ks) {
            const int ck = ks * 4 + quad;
            bfrag8 bfv[8];
            #pragma unroll
            for (int ni = 0; ni < 8; ++ni) {
                int row = wc + ni * 16 + qrow;
                bfv[ni] = *(const bfrag8*)&Ws[row * 64 + ((ck ^ (row & 7)) * 8)];
            }
            #pragma unroll
            for (int mi = 0; mi < 2; ++mi) {
                int l = wr + mi * 16 + qrow;
                union { bfrag8 v; unsigned short h[8]; } af;
                union { bf16 bh; unsigned short u; } cv;
                #pragma unroll
                for (int j = 0; j < 8; ++j) {
                    float f = Xs[(ck * 8 + j) * 64 + l];
                    cv.bh = __float2bfloat16(f);
                    af.h[j] = cv.u;
                }
                #pragma unroll
                for (int ni = 0; ni < 8; ++ni)
                    acc[mi][ni] = __builtin_amdgcn_mfma_f32_16x16x32_bf16(
                        af.v, bfv[ni], acc[mi][ni], 0, 0, 0);
            }
        }
        __syncthreads();
    }

    // D layout: col=lane&15, row=quad*4+reg  [m89-verified]
    const int bmr = l0 + wr, bnc = wc;
    bf16* Cp = KQt + (size_t)bz * 2048 * 256;
    #pragma unroll
    for (int mi = 0; mi < 2; ++mi) {
        #pragma unroll
        for (int ni = 0; ni < 8; ++ni) {
            int col = bnc + ni * 16 + qrow;
            float sc = scl[col], bb = b2[col];
            #pragma unroll
            for (int r = 0; r < 4; ++r) {
                int row = bmr + mi * 16 + quad * 4 + r;
                Cp[(size_t)row * 256 + col] = __float2bfloat16(acc[mi][ni][r] * sc + bb);
            }
        }
    }
}

// ---------------------------------------------------------------------------
// Stage-3 dedicated kernel: St8 = fp8((exp(S)-1)*4096), Z += colsum(exp(S)).
// S[m][l] = sum_k Q[m][k]*K[l][k], K=128 (single LDS shot, no dbuf).
// 256x256 tile, 512 threads (8 waves, 2Mx4N), 128KiB LDS, 2 barriers total.
// ---------------------------------------------------------------------------
__global__ __launch_bounds__(512, 2)
void gemm_s3(const bf16* __restrict__ Ag, long sAb, int lda,
             const bf16* __restrict__ Bg, long sBb, int ldb,
             unsigned char* __restrict__ Cg, long sCb, int ldc,
             float* __restrict__ Zp)
{
    __shared__ __align__(16) unsigned char smem[131072];   // As 64KB | Bs 64KB

    const int lin = blockIdx.x;
    const int bz  = lin & 7;              // one batch per XCD (KQt batch = 1MB, L2-resident)
    const int s0  = lin >> 3;             // 0..63
    const int nT  = s0 & 7, mT = s0 >> 3;

    const bf16* A  = Ag + (size_t)bz * sAb + (size_t)mT * 256 * lda;
    const bf16* Bp = Bg + (size_t)bz * sBb + (size_t)nT * 256 * ldb;
    const int t = threadIdx.x, wave = t >> 6, lane = t & 63;
    const int qrow = lane & 15, quad = lane >> 4;
    const int wm = (wave >> 2) * 128;     // 2 M-waves
    const int wn = (wave & 3) * 64;       // 4 N-waves

    unsigned char* As = smem;
    unsigned char* Bs = smem + 65536;

    // stage the full 256x128-elem (256B/row) A and B panels; 16 loads/thread
    #pragma unroll
    for (int j = 0; j < 8; ++j) {
        int c = j * 512 + t;
        int r = c >> 4, p = c & 15;
        int g = (p & 8) | ((p & 7) ^ (r & 7));
        async_copy16(A + (size_t)r * lda + g * 8, As + c * 16);
    }
    #pragma unroll
    for (int j = 0; j < 8; ++j) {
        int c = j * 512 + t;
        int r = c >> 4, p = c & 15;
        int g = (p & 8) | ((p & 7) ^ (r & 7));
        async_copy16(Bp + (size_t)r * ldb + g * 8, Bs + c * 16);
    }
    asm volatile("s_waitcnt vmcnt(0)" ::: "memory");
    __builtin_amdgcn_s_barrier();

    floatx4 acc[8][4] = {};
    #pragma unroll
    for (int ks = 0; ks < 4; ++ks) {
        const int ck = ks * 4 + quad;     // 16B k-chunk index, 0..15
        bfrag8 bfv[4];
        #pragma unroll
        for (int ni = 0; ni < 4; ++ni) {
            int row = wn + ni * 16 + qrow;
            int ph  = (ck & 8) | ((ck & 7) ^ (row & 7));
            bfv[ni] = *(const bfrag8*)&Bs[row * 256 + ph * 16];
        }
        #pragma unroll
        for (int mi = 0; mi < 8; ++mi) {
            int row = wm + mi * 16 + qrow;
            int ph  = (ck & 8) | ((ck & 7) ^ (row & 7));
            bfrag8 af = *(const bfrag8*)&As[row * 256 + ph * 16];
            #pragma unroll
            for (int ni = 0; ni < 4; ++ni)
                acc[mi][ni] = __builtin_amdgcn_mfma_f32_16x16x32_bf16(
                    af, bfv[ni], acc[mi][ni], 0, 0, 0);
        }
    }

    // D layout: col=lane&15, row=quad*4+reg  [m89-verified]
    const int bmr = mT * 256 + wm, bnc = nT * 256 + wn;
    unsigned char* C8 = Cg + (size_t)bz * sCb;
    float zp[4] = {0.f, 0.f, 0.f, 0.f};
    #pragma unroll
    for (int mi = 0; mi < 8; ++mi) {
        #pragma unroll
        for (int ni = 0; ni < 4; ++ni) {
            int col = bnc + ni * 16 + qrow;
            #pragma unroll
            for (int r = 0; r < 4; ++r) {
                int row = bmr + mi * 16 + quad * 4 + r;
                float e = __expf(acc[mi][ni][r]);
                zp[ni] += e;
                C8[(size_t)row * ldc + col] = f2fp8((e - 1.0f) * 4096.0f);
            }
        }
    }
    #pragma unroll
    for (int ni = 0; ni < 4; ++ni) {
        float tt = zp[ni];
        tt += __shfl_xor(tt, 16, 64);
        tt += __shfl_xor(tt, 32, 64);
        if (quad == 0)
            atomicAdd(&Zp[bz * 2048 + bnc + ni * 16 + qrow], tt);
    }
}

// ---------------------------------------------------------------------------
// fp8 MX GEMM (stages 5/6): 256x256 tile, 512 threads (8 waves, 2Mx4N),
// BK=128 bytes, 8-phase schedule (round-2/4 best variant; at the documented
// ~33% MX plateau - do not touch).
// MODE 0: fp8 out, v=acc*os.  MODE 2: f32 out, v=acc*os + rowb[bz*1024+row].
// ---------------------------------------------------------------------------
template<int MODE, bool MFAST>
__global__ __launch_bounds__(512, 2)
void gemm_f8(const unsigned char* __restrict__ Ag, long sAb, int lda,
             const unsigned char* __restrict__ Bg, long sBb, int ldb,
             void* __restrict__ Cg, long sCb, int ldc,
             const float* __restrict__ rowb, float os, int K, int logfast)
{
    // As[slot] = smem + slot*32768 ; Bs[slot] = smem + 65536 + slot*32768
    __shared__ __align__(16) unsigned char smem[131072];

    const int lin = blockIdx.x;
    const int bz  = lin & 7;              // one batch per XCD
    const int s0  = lin >> 3;
    const int msk = (1 << logfast) - 1;
    int mT, nT;
    if (MFAST) { mT = s0 & msk; nT = s0 >> logfast; }
    else       { nT = s0 & msk; mT = s0 >> logfast; }

    const unsigned char* A  = Ag + (size_t)bz * sAb + (size_t)mT * 256 * lda;
    const unsigned char* Bp = Bg + (size_t)bz * sBb + (size_t)nT * 256 * ldb;
    const int t = threadIdx.x, wave = t >> 6, lane = t & 63;
    const int qrow = lane & 15, quad = lane >> 4;
    const int wm = (wave >> 2) * 128;     // wave row base (2 M-waves)
    const int wn = (wave & 3) * 64;       // wave col base (4 N-waves)

    floatx4 acc[8][4] = {};

    // issue 4 of the 8 per-thread loads for tile kt into slot (part = 0 or 1).
    auto stage_part = [&](int kt, int slot, int part) {
        const int k0 = kt << 7;
        unsigned char* Ad = &smem[slot * 32768];
        unsigned char* Bd = &smem[65536 + slot * 32768];
        #pragma unroll
        for (int j = 0; j < 2; ++j) {
            int c = (part * 2 + j) * 512 + t;
            int r = c >> 3, p = c & 7, g = p ^ (r & 7);
            async_copy16(A + (size_t)r * lda + k0 + g * 16, Ad + c * 16);
        }
        #pragma unroll
        for (int j = 0; j < 2; ++j) {
            int c = (part * 2 + j) * 512 + t;
            int r = c >> 3, p = c & 7, g = p ^ (r & 7);
            async_copy16(Bp + (size_t)r * ldb + k0 + g * 16, Bd + c * 16);
        }
    };

    const int NT = K >> 7;
    stage_part(0, 0, 0);
    stage_part(0, 0, 1);

    for (int kt = 0; kt < NT; ++kt) {
        const int slot = kt & 1;
        const unsigned char* As = &smem[slot * 32768];
        const unsigned char* Bs = &smem[65536 + slot * 32768];

        // entry: tile kt's loads (issued during phases 0-1 of kt-1) landed.
        asm volatile("s_waitcnt vmcnt(0)" ::: "memory");
        __builtin_amdgcn_sched_barrier(0);
        __builtin_amdgcn_s_barrier();
        __builtin_amdgcn_sched_barrier(0);

        intx8 bfr[4];
        #pragma unroll
        for (int ph = 0; ph < 4; ++ph) {
            // ---- ds-read this phase's register subtile ----
            if (ph == 0) {
                #pragma unroll
                for (int ni = 0; ni < 4; ++ni) {
                    int row = wn + ni * 16 + qrow, sw = row & 7;
                    union { intx8 v; uint4 q[2]; } u;
                    u.q[0] = *(const uint4*)&Bs[row * 128 + (((quad * 2    ) ^ sw) * 16)];
                    u.q[1] = *(const uint4*)&Bs[row * 128 + (((quad * 2 + 1) ^ sw) * 16)];
                    bfr[ni] = u.v;
                }
            }
            intx8 af0, af1;
            {
                int row = wm + (2 * ph) * 16 + qrow, sw = row & 7;
                union { intx8 v; uint4 q[2]; } u;
                u.q[0] = *(const uint4*)&As[row * 128 + (((quad * 2    ) ^ sw) * 16)];
                u.q[1] = *(const uint4*)&As[row * 128 + (((quad * 2 + 1) ^ sw) * 16)];
                af0 = u.v;
            }
            {
                int row = wm + (2 * ph + 1) * 16 + qrow, sw = row & 7;
                union { intx8 v; uint4 q[2]; } u;
                u.q[0] = *(const uint4*)&As[row * 128 + (((quad * 2    ) ^ sw) * 16)];
                u.q[1] = *(const uint4*)&As[row * 128 + (((quad * 2 + 1) ^ sw) * 16)];
                af1 = u.v;
            }
            // ---- stage next tile's loads early (phases 0-1) ----
            if (ph < 2 && kt + 1 < NT) stage_part(kt + 1, slot ^ 1, ph);

            __builtin_amdgcn_sched_barrier(0);
            __builtin_amdgcn_s_barrier();
            asm volatile("s_waitcnt lgkmcnt(0)" ::: "memory");
            __builtin_amdgcn_sched_barrier(0);

            __builtin_amdgcn_s_setprio(1);
            #pragma unroll
            for (int ni = 0; ni < 4; ++ni)
                acc[2 * ph][ni] = __builtin_amdgcn_mfma_scale_f32_16x16x128_f8f6f4(
                    af0, bfr[ni], acc[2 * ph][ni], 0, 0, 0, 127, 0, 127);
            #pragma unroll
            for (int ni = 0; ni < 4; ++ni)
                acc[2 * ph + 1][ni] = __builtin_amdgcn_mfma_scale_f32_16x16x128_f8f6f4(
                    af1, bfr[ni], acc[2 * ph + 1][ni], 0, 0, 0, 127, 0, 127);
            __builtin_amdgcn_s_setprio(0);

            __builtin_amdgcn_sched_barrier(0);
            __builtin_amdgcn_s_barrier();
            __builtin_amdgcn_sched_barrier(0);
        }
    }

    // D layout: col=lane&15, row=quad*4+reg  [shape-determined, dtype-independent]
    const int bmr = mT * 256 + wm, bnc = nT * 256 + wn;
    #pragma unroll
    for (int mi = 0; mi < 8; ++mi) {
        int row0 = bmr + mi * 16 + quad * 4;
        float4 rb4;
        if (MODE == 2) rb4 = *(const float4*)&rowb[bz * 1024 + row0];
        #pragma unroll
        for (int ni = 0; ni < 4; ++ni) {
            int col = bnc + ni * 16 + qrow;
            floatx4 a = acc[mi][ni];
            if (MODE == 2) {
                float* Co = (float*)Cg + (size_t)bz * sCb;
                Co[(size_t)(row0 + 0) * ldc + col] = a[0] * os + rb4.x;
                Co[(size_t)(row0 + 1) * ldc + col] = a[1] * os + rb4.y;
                Co[(size_t)(row0 + 2) * ldc + col] = a[2] * os + rb4.z;
                Co[(size_t)(row0 + 3) * ldc + col] = a[3] * os + rb4.w;
            } else {
                unsigned char* C8 = (unsigned char*)Cg + (size_t)bz * sCb;
                #pragma unroll
                for (int r = 0; r < 4; ++r)
                    C8[(size_t)(row0 + r) * ldc + col] = f2fp8(a[r] * os);
            }
        }
    }
}

// Merged: conv_w (blocks 0-639) + prep_bias (block 640) + Z zeroing (641-644).
// Wk,Wq -> Wkqb bf16 (concat 256 rows); Wp -> Wp8 fp8 (*2^11). 8 elems/thread.
__global__ __launch_bounds__(256)
void conv_wz(const float* __restrict__ Wk, const float* __restrict__ Wq,
             const float* __restrict__ Wp, bf16* __restrict__ Wkqb,
             unsigned char* __restrict__ Wp8,
             const float* __restrict__ bk, const float* __restrict__ bq,
             float* __restrict__ scl, float* __restrict__ b2,
             float* __restrict__ Z, float kscale)
{
    const int blk = blockIdx.x;
    const int t   = threadIdx.x;
    if (blk == 640) {                      // prep_bias
        float s = (t < 128) ? kscale : 1.0f;
        scl[t] = s;
        b2[t] = ((t < 128) ? bk[t] : bq[t - 128]) * s;
        return;
    }
    if (blk >= 641) {                      // zero Z: 4 blocks x 256 thr x 16 floats
        float4 z = make_float4(0.f, 0.f, 0.f, 0.f);
        float* zp = Z + (size_t)(blk - 641) * 4096 + t * 16;
        #pragma unroll
        for (int j = 0; j < 4; ++j) *(float4*)(zp + j * 4) = z;
        return;
    }
    int i = blk * 256 + t;
    if (i < 32768) {
        const float* src = (i < 16384) ? Wk : Wq;
        int off = (i < 16384) ? i : i - 16384;
        bf16* dst = Wkqb + (size_t)((i < 16384) ? 0 : 131072);
        const float4* sp = (const float4*)src + (size_t)off * 2;
        float4 a = sp[0], b = sp[1];
        union { uint4 u; unsigned short h[8]; } o;
        union { bf16 h; unsigned short u; } cv;
        cv.h = __float2bfloat16(a.x); o.h[0] = cv.u;
        cv.h = __float2bfloat16(a.y); o.h[1] = cv.u;
        cv.h = __float2bfloat16(a.z); o.h[2] = cv.u;
        cv.h = __float2bfloat16(a.w); o.h[3] = cv.u;
        cv.h = __float2bfloat16(b.x); o.h[4] = cv.u;
        cv.h = __float2bfloat16(b.y); o.h[5] = cv.u;
        cv.h = __float2bfloat16(b.z); o.h[6] = cv.u;
        cv.h = __float2bfloat16(b.w); o.h[7] = cv.u;
        ((uint4*)dst)[off] = o.u;
    } else {
        int off = i - 32768;   // Wp: 131072 chunks
        const float4* sp = (const float4*)Wp + (size_t)off * 2;
        float4 a = sp[0], b = sp[1];
        unsigned char o[8];
        o[0] = f2fp8(a.x * 2048.f); o[1] = f2fp8(a.y * 2048.f);
        o[2] = f2fp8(a.z * 2048.f); o[3] = f2fp8(a.w * 2048.f);
        o[4] = f2fp8(b.x * 2048.f); o[5] = f2fp8(b.y * 2048.f);
        o[6] = f2fp8(b.z * 2048.f); o[7] = f2fp8(b.w * 2048.f);
        uint2 w;
        w.x = (unsigned int)o[0] | ((unsigned int)o[1] << 8) | ((unsigned int)o[2] << 16) | ((unsigned int)o[3] << 24);
        w.y = (unsigned int)o[4] | ((unsigned int)o[5] << 8) | ((unsigned int)o[6] << 16) | ((unsigned int)o[7] << 24);
        ((uint2*)Wp8)[off] = w;
    }
}

// xs8[b][c][l] = fp8(x/Z * 2^16); colsum[b][c] = sum_l x/Z (exact fp32).
__global__ __launch_bounds__(256)
void normx(const float* __restrict__ x, const float* __restrict__ Z,
           unsigned char* __restrict__ xs, float* __restrict__ colsum)
{
    const int bc = blockIdx.x;            // b*1024 + c
    const int b  = bc >> 10;
    const int t  = threadIdx.x;
    const float* xp = x + (size_t)bc * 2048 + t * 8;
    const float* zp = Z + b * 2048 + t * 8;
    float4 a = ((const float4*)xp)[0], c4 = ((const float4*)xp)[1];
    float4 z0 = ((const float4*)zp)[0], z1 = ((const float4*)zp)[1];
    float v[8];
    v[0] = a.x  / fmaxf(z0.x, 1e-10f); v[1] = a.y / fmaxf(z0.y, 1e-10f);
    v[2] = a.z  / fmaxf(z0.z, 1e-10f); v[3] = a.w / fmaxf(z0.w, 1e-10f);
    v[4] = c4.x / fmaxf(z1.x, 1e-10f); v[5] = c4.y / fmaxf(z1.y, 1e-10f);
    v[6] = c4.z / fmaxf(z1.z, 1e-10f); v[7] = c4.w / fmaxf(z1.w, 1e-10f);
    float s = 0.f;
    unsigned char o[8];
    #pragma unroll
    for (int j = 0; j < 8; ++j) { s += v[j]; o[j] = f2fp8(v[j] * 65536.f); }
    uint2 w;
    w.x = (unsigned int)o[0] | ((unsigned int)o[1] << 8) | ((unsigned int)o[2] << 16) | ((unsigned int)o[3] << 24);
    w.y = (unsigned int)o[4] | ((unsigned int)o[5] << 8) | ((unsigned int)o[6] << 16) | ((unsigned int)o[7] << 24);
    ((uint2*)(xs + (size_t)bc * 2048))[t] = w;
    #pragma unroll
    for (int off = 32; off >= 1; off >>= 1) s += __shfl_xor(s, off, 64);
    __shared__ float red[4];
    if ((t & 63) == 0) red[t >> 6] = s;
    __syncthreads();
    if (t == 0) colsum[bc] = red[0] + red[1] + red[2] + red[3];
}

// base[b][d] = bp[d] + sum_c Wp[d,c]*colsum[b][c]  (exact fp32 path)
__global__ __launch_bounds__(256)
void basek(const float* __restrict__ Wp, const float* __restrict__ colsum,
           const float* __restrict__ bp, float* __restrict__ base)
{
    const int d = blockIdx.x, t = threadIdx.x;
    float4 w = *(const float4*)(Wp + (size_t)d * 1024 + t * 4);
    float pb[8];
    #pragma unroll
    for (int b = 0; b < 8; ++b) {
        float4 cs = *(const float4*)(colsum + b * 1024 + t * 4);
        pb[b] = w.x * cs.x + w.y * cs.y + w.z * cs.z + w.w * cs.w;
    }
    __shared__ float red[8][4];
    #pragma unroll
    for (int b = 0; b < 8; ++b) {
        float s = pb[b];
        #pragma unroll
        for (int off = 32; off >= 1; off >>= 1) s += __shfl_xor(s, off, 64);
        if ((t & 63) == 0) red[b][t >> 6] = s;
    }
    __syncthreads();
    if (t < 8) base[t * 1024 + d] = bp[d] + red[t][0] + red[t][1] + red[t][2] + red[t][3];
}

extern "C" void kernel_launch(void* const* d_in, const int* in_sizes, int n_in,
                              void* d_out, int out_size, void* d_ws, size_t ws_size,
                              hipStream_t stream)
{
    const float* x  = (const float*)d_in[0];
    const float* Wk = (const float*)d_in[1];
    const float* bk = (const float*)d_in[2];
    const float* Wq = (const float*)d_in[3];
    const float* bq = (const float*)d_in[4];
    const float* Wp = (const float*)d_in[5];
    const float* bp = (const float*)d_in[6];
    float* out = (float*)d_out;

    const float kscale = 2.0f / 2048.0f;

    // ws layout (xt slot retained for Dlt alias): Dlt 16.8MB (in old xt slot) |
    // KQt bf16 8.4MB | Wkqb bf16 0.5MB | Wp8 1MB | St8 33.5MB | xs8 16.8MB | floats
    bf16* xt   = (bf16*)d_ws;                                // slot reused by Dlt
    bf16* KQt  = xt + (size_t)8 * 2048 * 1024;
    bf16* Wkqb = KQt + (size_t)8 * 2048 * 256;
    unsigned char* Wp8 = (unsigned char*)(Wkqb + (size_t)256 * 1024);
    unsigned char* St8 = Wp8 + (size_t)1048576;              // [b][m][l]
    unsigned char* xs8 = St8 + (size_t)8 * 2048 * 2048;      // [b][c][l]
    float* Z      = (float*)(xs8 + (size_t)8 * 1024 * 2048); // [b][2048]
    float* colsum = Z + 8 * 2048;
    float* base   = colsum + 8 * 1024;
    float* scl    = base + 8 * 1024;
    float* b2     = scl + 256;
    unsigned char* Dlt = (unsigned char*)d_ws;               // [b][m][c]

    dim3 blk(256, 1, 1);
    dim3 blk512(512, 1, 1);

    // weights conv + bias prep + Z zero, one dispatch
    conv_wz<<<dim3(645), blk, 0, stream>>>(Wk, Wq, Wp, Wkqb, Wp8,
                                           bk, bq, scl, b2, Z, kscale);

    // stage 1+2 FUSED with x transpose: KQt[l][0:128]=K*kscale, [128:256]=Q
    // grid: 8 bz x 32 mT = 256 blocks; x read once.
    gemm12<<<dim3(256), blk, 0, stream>>>(x, Wkqb, KQt, scl, b2);

    // stage 3 (dedicated 256^2 single-shot): St8[m][l] = fp8((exp(v)-1)*2^12);
    // Z[l] += col sums of exp (exact fp32). grid: 8 x (8x8) = 512 blocks
    gemm_s3<<<dim3(8 * 8 * 8), blk512, 0, stream>>>(
        KQt + 128, 2048L * 256, 256,  KQt, 2048L * 256, 256,
        St8, 2048L * 2048, 2048,  Z);

    normx<<<dim3(8 * 1024), blk, 0, stream>>>(x, Z, xs8, colsum);
    basek<<<dim3(1024), blk, 0, stream>>>(Wp, colsum, bp, base);

    // stage 5 (fp8 MX, 256^2 8-phase): Dlt[m][c] = fp8(acc*2^-10)
    gemm_f8<0, false><<<dim3(8 * 8 * 4), blk512, 0, stream>>>(
        St8, 2048L * 2048, 2048,  xs8, 1024L * 2048, 2048,
        Dlt, 2048L * 1024, 1024,  nullptr, 0.0009765625f, 2048, 2);

    // stage 6 (fp8 MX, 256^2 8-phase): out[d][m] = acc*2^-29 + base[b][d]
    gemm_f8<2, true><<<dim3(8 * 4 * 8), blk512, 0, stream>>>(
        Wp8, 0, 1024,  Dlt, 2048L * 1024, 1024,
        out, 1024L * 2048, 2048,  base, 1.862645149230957e-9f, 1024, 2);
}

// Round 6
// 244.880 us; speedup vs baseline: 1.1110x; 1.0020x over previous
//
#include <hip/hip_runtime.h>
#include <hip/hip_bf16.h>

typedef __hip_bfloat16 bf16;
typedef __attribute__((ext_vector_type(8))) short bfrag8;   // 8 bf16 (MFMA A/B frag)
typedef __attribute__((ext_vector_type(8))) int intx8;      // 32 fp8 bytes (MX frag)
typedef __attribute__((ext_vector_type(4))) float floatx4;  // MFMA C/D frag

// Scale ladder (powers of 2, folded exactly in fp32 epilogues):
//   Wp8 = Wp*2^11 ; St8 = (exp(v)-1)*2^12 ; xs8 = (x/Z)*2^16
//   Dlt = acc5*2^-10 (= Delta*2^18) ; out = acc6*2^-29 + base[d]

__device__ __forceinline__ unsigned char f2fp8(float f) {
    f = fminf(fmaxf(f, -448.f), 448.f);            // clamp: overflow->NaN is the r5 killer
    return (unsigned char)(__builtin_amdgcn_cvt_pk_fp8_f32(f, f, 0, false) & 0xFF);
}

__device__ __forceinline__ void async_copy16(const void* g, void* lds) {
    __builtin_amdgcn_global_load_lds(
        (const __attribute__((address_space(1))) unsigned int*)g,
        (__attribute__((address_space(3))) unsigned int*)lds, 16, 0, 0);
}

// ---------------------------------------------------------------------------
// Stage 1+2 FUSED with the x transpose (replaces conv_x + gemm128):
// KQt[l][a] = (sum_c bf16(x[c][l]) * Wkqb[a][c]) * scl[a] + b2[a]
// Tile: 64 l (M) x 256 a (N, full) per block; grid 8 bz x 32 mT = 256 blocks.
// ROUND 6: DOUBLE-BUFFERED staging (was serialized stage->vmcnt(0)->compute
// per K-step, ~2100cyc stage + ~1900cyc compute back-to-back). Now the
// gemm_f8-proven entry pattern: vmcnt(0) waits loads issued one full
// compute-phase earlier -> per-step cost = max(stage, compute).
// Race audit: iter kt+1 stages into slot(kt&1) only after its entry
// barrier; all reads of that slot (iter kt) are MFMA-consumed before any
// wave reaches that barrier (compiler lgkm waits precede consumption).
// Numerics BIT-IDENTICAL: same bf16 cvt per element, same accumulation
// order, same epilogue.
// ---------------------------------------------------------------------------
__global__ __launch_bounds__(256)
void gemm12(const float* __restrict__ xg, const bf16* __restrict__ Wkqb,
            bf16* __restrict__ KQt, const float* __restrict__ scl,
            const float* __restrict__ b2)
{
    __shared__ __align__(16) float Xs[2][64 * 64];            // [c][l] 16KB x2, linear
    __shared__ __align__(16) unsigned short Ws[2][256 * 64];  // [a][c] 32KB x2, swizzled

    const int lin = blockIdx.x;
    const int bz  = lin & 7;              // one batch per XCD
    const int mT  = lin >> 3;             // 0..31
    const int l0  = mT * 64;
    const float* xp = xg + (size_t)bz * 1024 * 2048;

    const int t = threadIdx.x, wave = t >> 6, lane = t & 63;
    const int qrow = lane & 15, quad = lane >> 4;
    const int wr = (wave >> 1) * 32, wc = (wave & 1) * 128;

    floatx4 acc[2][8] = {};

    // stage K-step kt into LDS slot: Xs 64c x 64l f32 (linear) + Ws 256a x 64c
    // bf16 (swizzled). 12 global_load_lds per thread.
    auto stage = [&](int kt, int slot) {
        const int k0 = kt << 6;
        #pragma unroll
        for (int j = 0; j < 4; ++j) {
            int ci = j * 256 + t;
            int r = ci >> 4, li = (ci & 15) * 4;
            async_copy16(xp + (size_t)(k0 + r) * 2048 + l0 + li, &Xs[slot][ci * 4]);
        }
        #pragma unroll
        for (int j = 0; j < 8; ++j) {
            int ci = j * 256 + t;
            int r = ci >> 3, p = ci & 7, g = p ^ (r & 7);
            async_copy16(Wkqb + (size_t)r * 1024 + k0 + g * 8, &Ws[slot][ci * 8]);
        }
    };

    stage(0, 0);

    for (int kt = 0; kt < 16; ++kt) {
        const int slot = kt & 1;

        // entry: prefetched loads for this slot landed (issued 1 iter ago).
        asm volatile("s_waitcnt vmcnt(0)" ::: "memory");
        __builtin_amdgcn_sched_barrier(0);
        __builtin_amdgcn_s_barrier();
        __builtin_amdgcn_sched_barrier(0);

        if (kt + 1 < 16) stage(kt + 1, slot ^ 1);   // overlap with compute below

        #pragma unroll
        for (int ks = 0; ks < 2; ++ks) {
            const int ck = ks * 4 + quad;
            bfrag8 bfv[8];
            #pragma unroll
            for (int ni = 0; ni < 8; ++ni) {
                int row = wc + ni * 16 + qrow;
                bfv[ni] = *(const bfrag8*)&Ws[slot][row * 64 + ((ck ^ (row & 7)) * 8)];
            }
            #pragma unroll
            for (int mi = 0; mi < 2; ++mi) {
                int l = wr + mi * 16 + qrow;
                union { bfrag8 v; unsigned short h[8]; } af;
                union { bf16 bh; unsigned short u; } cv;
                #pragma unroll
                for (int j = 0; j < 8; ++j) {
                    float f = Xs[slot][(ck * 8 + j) * 64 + l];
                    cv.bh = __float2bfloat16(f);
                    af.h[j] = cv.u;
                }
                #pragma unroll
                for (int ni = 0; ni < 8; ++ni)
                    acc[mi][ni] = __builtin_amdgcn_mfma_f32_16x16x32_bf16(
                        af.v, bfv[ni], acc[mi][ni], 0, 0, 0);
            }
        }
    }

    // D layout: col=lane&15, row=quad*4+reg  [m89-verified]
    const int bmr = l0 + wr, bnc = wc;
    bf16* Cp = KQt + (size_t)bz * 2048 * 256;
    #pragma unroll
    for (int mi = 0; mi < 2; ++mi) {
        #pragma unroll
        for (int ni = 0; ni < 8; ++ni) {
            int col = bnc + ni * 16 + qrow;
            float sc = scl[col], bb = b2[col];
            #pragma unroll
            for (int r = 0; r < 4; ++r) {
                int row = bmr + mi * 16 + quad * 4 + r;
                Cp[(size_t)row * 256 + col] = __float2bfloat16(acc[mi][ni][r] * sc + bb);
            }
        }
    }
}

// ---------------------------------------------------------------------------
// Stage-3 dedicated kernel: St8 = fp8((exp(S)-1)*4096), Z += colsum(exp(S)).
// S[m][l] = sum_k Q[m][k]*K[l][k], K=128 (single LDS shot, no dbuf).
// 256x256 tile, 512 threads (8 waves, 2Mx4N), 128KiB LDS, 2 barriers total.
// ---------------------------------------------------------------------------
__global__ __launch_bounds__(512, 2)
void gemm_s3(const bf16* __restrict__ Ag, long sAb, int lda,
             const bf16* __restrict__ Bg, long sBb, int ldb,
             unsigned char* __restrict__ Cg, long sCb, int ldc,
             float* __restrict__ Zp)
{
    __shared__ __align__(16) unsigned char smem[131072];   // As 64KB | Bs 64KB

    const int lin = blockIdx.x;
    const int bz  = lin & 7;              // one batch per XCD (KQt batch = 1MB, L2-resident)
    const int s0  = lin >> 3;             // 0..63
    const int nT  = s0 & 7, mT = s0 >> 3;

    const bf16* A  = Ag + (size_t)bz * sAb + (size_t)mT * 256 * lda;
    const bf16* Bp = Bg + (size_t)bz * sBb + (size_t)nT * 256 * ldb;
    const int t = threadIdx.x, wave = t >> 6, lane = t & 63;
    const int qrow = lane & 15, quad = lane >> 4;
    const int wm = (wave >> 2) * 128;     // 2 M-waves
    const int wn = (wave & 3) * 64;       // 4 N-waves

    unsigned char* As = smem;
    unsigned char* Bs = smem + 65536;

    // stage the full 256x128-elem (256B/row) A and B panels; 16 loads/thread
    #pragma unroll
    for (int j = 0; j < 8; ++j) {
        int c = j * 512 + t;
        int r = c >> 4, p = c & 15;
        int g = (p & 8) | ((p & 7) ^ (r & 7));
        async_copy16(A + (size_t)r * lda + g * 8, As + c * 16);
    }
    #pragma unroll
    for (int j = 0; j < 8; ++j) {
        int c = j * 512 + t;
        int r = c >> 4, p = c & 15;
        int g = (p & 8) | ((p & 7) ^ (r & 7));
        async_copy16(Bp + (size_t)r * ldb + g * 8, Bs + c * 16);
    }
    asm volatile("s_waitcnt vmcnt(0)" ::: "memory");
    __builtin_amdgcn_s_barrier();

    floatx4 acc[8][4] = {};
    #pragma unroll
    for (int ks = 0; ks < 4; ++ks) {
        const int ck = ks * 4 + quad;     // 16B k-chunk index, 0..15
        bfrag8 bfv[4];
        #pragma unroll
        for (int ni = 0; ni < 4; ++ni) {
            int row = wn + ni * 16 + qrow;
            int ph  = (ck & 8) | ((ck & 7) ^ (row & 7));
            bfv[ni] = *(const bfrag8*)&Bs[row * 256 + ph * 16];
        }
        #pragma unroll
        for (int mi = 0; mi < 8; ++mi) {
            int row = wm + mi * 16 + qrow;
            int ph  = (ck & 8) | ((ck & 7) ^ (row & 7));
            bfrag8 af = *(const bfrag8*)&As[row * 256 + ph * 16];
            #pragma unroll
            for (int ni = 0; ni < 4; ++ni)
                acc[mi][ni] = __builtin_amdgcn_mfma_f32_16x16x32_bf16(
                    af, bfv[ni], acc[mi][ni], 0, 0, 0);
        }
    }

    // D layout: col=lane&15, row=quad*4+reg  [m89-verified]
    const int bmr = mT * 256 + wm, bnc = nT * 256 + wn;
    unsigned char* C8 = Cg + (size_t)bz * sCb;
    float zp[4] = {0.f, 0.f, 0.f, 0.f};
    #pragma unroll
    for (int mi = 0; mi < 8; ++mi) {
        #pragma unroll
        for (int ni = 0; ni < 4; ++ni) {
            int col = bnc + ni * 16 + qrow;
            #pragma unroll
            for (int r = 0; r < 4; ++r) {
                int row = bmr + mi * 16 + quad * 4 + r;
                float e = __expf(acc[mi][ni][r]);
                zp[ni] += e;
                C8[(size_t)row * ldc + col] = f2fp8((e - 1.0f) * 4096.0f);
            }
        }
    }
    #pragma unroll
    for (int ni = 0; ni < 4; ++ni) {
        float tt = zp[ni];
        tt += __shfl_xor(tt, 16, 64);
        tt += __shfl_xor(tt, 32, 64);
        if (quad == 0)
            atomicAdd(&Zp[bz * 2048 + bnc + ni * 16 + qrow], tt);
    }
}

// ---------------------------------------------------------------------------
// fp8 MX GEMM (stages 5/6): 256x256 tile, 512 threads (8 waves, 2Mx4N),
// BK=128 bytes, 8-phase schedule (round-2/4 best variant; at the documented
// ~33% MX plateau - do not touch).
// MODE 0: fp8 out, v=acc*os.  MODE 2: f32 out, v=acc*os + rowb[bz*1024+row].
// ---------------------------------------------------------------------------
template<int MODE, bool MFAST>
__global__ __launch_bounds__(512, 2)
void gemm_f8(const unsigned char* __restrict__ Ag, long sAb, int lda,
             const unsigned char* __restrict__ Bg, long sBb, int ldb,
             void* __restrict__ Cg, long sCb, int ldc,
             const float* __restrict__ rowb, float os, int K, int logfast)
{
    // As[slot] = smem + slot*32768 ; Bs[slot] = smem + 65536 + slot*32768
    __shared__ __align__(16) unsigned char smem[131072];

    const int lin = blockIdx.x;
    const int bz  = lin & 7;              // one batch per XCD
    const int s0  = lin >> 3;
    const int msk = (1 << logfast) - 1;
    int mT, nT;
    if (MFAST) { mT = s0 & msk; nT = s0 >> logfast; }
    else       { nT = s0 & msk; mT = s0 >> logfast; }

    const unsigned char* A  = Ag + (size_t)bz * sAb + (size_t)mT * 256 * lda;
    const unsigned char* Bp = Bg + (size_t)bz * sBb + (size_t)nT * 256 * ldb;
    const int t = threadIdx.x, wave = t >> 6, lane = t & 63;
    const int qrow = lane & 15, quad = lane >> 4;
    const int wm = (wave >> 2) * 128;     // wave row base (2 M-waves)
    const int wn = (wave & 3) * 64;       // wave col base (4 N-waves)

    floatx4 acc[8][4] = {};

    // issue 4 of the 8 per-thread loads for tile kt into slot (part = 0 or 1).
    auto stage_part = [&](int kt, int slot, int part) {
        const int k0 = kt << 7;
        unsigned char* Ad = &smem[slot * 32768];
        unsigned char* Bd = &smem[65536 + slot * 32768];
        #pragma unroll
        for (int j = 0; j < 2; ++j) {
            int c = (part * 2 + j) * 512 + t;
            int r = c >> 3, p = c & 7, g = p ^ (r & 7);
            async_copy16(A + (size_t)r * lda + k0 + g * 16, Ad + c * 16);
        }
        #pragma unroll
        for (int j = 0; j < 2; ++j) {
            int c = (part * 2 + j) * 512 + t;
            int r = c >> 3, p = c & 7, g = p ^ (r & 7);
            async_copy16(Bp + (size_t)r * ldb + k0 + g * 16, Bd + c * 16);
        }
    };

    const int NT = K >> 7;
    stage_part(0, 0, 0);
    stage_part(0, 0, 1);

    for (int kt = 0; kt < NT; ++kt) {
        const int slot = kt & 1;
        const unsigned char* As = &smem[slot * 32768];
        const unsigned char* Bs = &smem[65536 + slot * 32768];

        // entry: tile kt's loads (issued during phases 0-1 of kt-1) landed.
        asm volatile("s_waitcnt vmcnt(0)" ::: "memory");
        __builtin_amdgcn_sched_barrier(0);
        __builtin_amdgcn_s_barrier();
        __builtin_amdgcn_sched_barrier(0);

        intx8 bfr[4];
        #pragma unroll
        for (int ph = 0; ph < 4; ++ph) {
            // ---- ds-read this phase's register subtile ----
            if (ph == 0) {
                #pragma unroll
                for (int ni = 0; ni < 4; ++ni) {
                    int row = wn + ni * 16 + qrow, sw = row & 7;
                    union { intx8 v; uint4 q[2]; } u;
                    u.q[0] = *(const uint4*)&Bs[row * 128 + (((quad * 2    ) ^ sw) * 16)];
                    u.q[1] = *(const uint4*)&Bs[row * 128 + (((quad * 2 + 1) ^ sw) * 16)];
                    bfr[ni] = u.v;
                }
            }
            intx8 af0, af1;
            {
                int row = wm + (2 * ph) * 16 + qrow, sw = row & 7;
                union { intx8 v; uint4 q[2]; } u;
                u.q[0] = *(const uint4*)&As[row * 128 + (((quad * 2    ) ^ sw) * 16)];
                u.q[1] = *(const uint4*)&As[row * 128 + (((quad * 2 + 1) ^ sw) * 16)];
                af0 = u.v;
            }
            {
                int row = wm + (2 * ph + 1) * 16 + qrow, sw = row & 7;
                union { intx8 v; uint4 q[2]; } u;
                u.q[0] = *(const uint4*)&As[row * 128 + (((quad * 2    ) ^ sw) * 16)];
                u.q[1] = *(const uint4*)&As[row * 128 + (((quad * 2 + 1) ^ sw) * 16)];
                af1 = u.v;
            }
            // ---- stage next tile's loads early (phases 0-1) ----
            if (ph < 2 && kt + 1 < NT) stage_part(kt + 1, slot ^ 1, ph);

            __builtin_amdgcn_sched_barrier(0);
            __builtin_amdgcn_s_barrier();
            asm volatile("s_waitcnt lgkmcnt(0)" ::: "memory");
            __builtin_amdgcn_sched_barrier(0);

            __builtin_amdgcn_s_setprio(1);
            #pragma unroll
            for (int ni = 0; ni < 4; ++ni)
                acc[2 * ph][ni] = __builtin_amdgcn_mfma_scale_f32_16x16x128_f8f6f4(
                    af0, bfr[ni], acc[2 * ph][ni], 0, 0, 0, 127, 0, 127);
            #pragma unroll
            for (int ni = 0; ni < 4; ++ni)
                acc[2 * ph + 1][ni] = __builtin_amdgcn_mfma_scale_f32_16x16x128_f8f6f4(
                    af1, bfr[ni], acc[2 * ph + 1][ni], 0, 0, 0, 127, 0, 127);
            __builtin_amdgcn_s_setprio(0);

            __builtin_amdgcn_sched_barrier(0);
            __builtin_amdgcn_s_barrier();
            __builtin_amdgcn_sched_barrier(0);
        }
    }

    // D layout: col=lane&15, row=quad*4+reg  [shape-determined, dtype-independent]
    const int bmr = mT * 256 + wm, bnc = nT * 256 + wn;
    #pragma unroll
    for (int mi = 0; mi < 8; ++mi) {
        int row0 = bmr + mi * 16 + quad * 4;
        float4 rb4;
        if (MODE == 2) rb4 = *(const float4*)&rowb[bz * 1024 + row0];
        #pragma unroll
        for (int ni = 0; ni < 4; ++ni) {
            int col = bnc + ni * 16 + qrow;
            floatx4 a = acc[mi][ni];
            if (MODE == 2) {
                float* Co = (float*)Cg + (size_t)bz * sCb;
                Co[(size_t)(row0 + 0) * ldc + col] = a[0] * os + rb4.x;
                Co[(size_t)(row0 + 1) * ldc + col] = a[1] * os + rb4.y;
                Co[(size_t)(row0 + 2) * ldc + col] = a[2] * os + rb4.z;
                Co[(size_t)(row0 + 3) * ldc + col] = a[3] * os + rb4.w;
            } else {
                unsigned char* C8 = (unsigned char*)Cg + (size_t)bz * sCb;
                #pragma unroll
                for (int r = 0; r < 4; ++r)
                    C8[(size_t)(row0 + r) * ldc + col] = f2fp8(a[r] * os);
            }
        }
    }
}

// Merged: conv_w (blocks 0-639) + prep_bias (block 640) + Z zeroing (641-644).
// Wk,Wq -> Wkqb bf16 (concat 256 rows); Wp -> Wp8 fp8 (*2^11). 8 elems/thread.
__global__ __launch_bounds__(256)
void conv_wz(const float* __restrict__ Wk, const float* __restrict__ Wq,
             const float* __restrict__ Wp, bf16* __restrict__ Wkqb,
             unsigned char* __restrict__ Wp8,
             const float* __restrict__ bk, const float* __restrict__ bq,
             float* __restrict__ scl, float* __restrict__ b2,
             float* __restrict__ Z, float kscale)
{
    const int blk = blockIdx.x;
    const int t   = threadIdx.x;
    if (blk == 640) {                      // prep_bias
        float s = (t < 128) ? kscale : 1.0f;
        scl[t] = s;
        b2[t] = ((t < 128) ? bk[t] : bq[t - 128]) * s;
        return;
    }
    if (blk >= 641) {                      // zero Z: 4 blocks x 256 thr x 16 floats
        float4 z = make_float4(0.f, 0.f, 0.f, 0.f);
        float* zp = Z + (size_t)(blk - 641) * 4096 + t * 16;
        #pragma unroll
        for (int j = 0; j < 4; ++j) *(float4*)(zp + j * 4) = z;
        return;
    }
    int i = blk * 256 + t;
    if (i < 32768) {
        const float* src = (i < 16384) ? Wk : Wq;
        int off = (i < 16384) ? i : i - 16384;
        bf16* dst = Wkqb + (size_t)((i < 16384) ? 0 : 131072);
        const float4* sp = (const float4*)src + (size_t)off * 2;
        float4 a = sp[0], b = sp[1];
        union { uint4 u; unsigned short h[8]; } o;
        union { bf16 h; unsigned short u; } cv;
        cv.h = __float2bfloat16(a.x); o.h[0] = cv.u;
        cv.h = __float2bfloat16(a.y); o.h[1] = cv.u;
        cv.h = __float2bfloat16(a.z); o.h[2] = cv.u;
        cv.h = __float2bfloat16(a.w); o.h[3] = cv.u;
        cv.h = __float2bfloat16(b.x); o.h[4] = cv.u;
        cv.h = __float2bfloat16(b.y); o.h[5] = cv.u;
        cv.h = __float2bfloat16(b.z); o.h[6] = cv.u;
        cv.h = __float2bfloat16(b.w); o.h[7] = cv.u;
        ((uint4*)dst)[off] = o.u;
    } else {
        int off = i - 32768;   // Wp: 131072 chunks
        const float4* sp = (const float4*)Wp + (size_t)off * 2;
        float4 a = sp[0], b = sp[1];
        unsigned char o[8];
        o[0] = f2fp8(a.x * 2048.f); o[1] = f2fp8(a.y * 2048.f);
        o[2] = f2fp8(a.z * 2048.f); o[3] = f2fp8(a.w * 2048.f);
        o[4] = f2fp8(b.x * 2048.f); o[5] = f2fp8(b.y * 2048.f);
        o[6] = f2fp8(b.z * 2048.f); o[7] = f2fp8(b.w * 2048.f);
        uint2 w;
        w.x = (unsigned int)o[0] | ((unsigned int)o[1] << 8) | ((unsigned int)o[2] << 16) | ((unsigned int)o[3] << 24);
        w.y = (unsigned int)o[4] | ((unsigned int)o[5] << 8) | ((unsigned int)o[6] << 16) | ((unsigned int)o[7] << 24);
        ((uint2*)Wp8)[off] = w;
    }
}

// xs8[b][c][l] = fp8(x/Z * 2^16); colsum[b][c] = sum_l x/Z (exact fp32).
__global__ __launch_bounds__(256)
void normx(const float* __restrict__ x, const float* __restrict__ Z,
           unsigned char* __restrict__ xs, float* __restrict__ colsum)
{
    const int bc = blockIdx.x;            // b*1024 + c
    const int b  = bc >> 10;
    const int t  = threadIdx.x;
    const float* xp = x + (size_t)bc * 2048 + t * 8;
    const float* zp = Z + b * 2048 + t * 8;
    float4 a = ((const float4*)xp)[0], c4 = ((const float4*)xp)[1];
    float4 z0 = ((const float4*)zp)[0], z1 = ((const float4*)zp)[1];
    float v[8];
    v[0] = a.x  / fmaxf(z0.x, 1e-10f); v[1] = a.y / fmaxf(z0.y, 1e-10f);
    v[2] = a.z  / fmaxf(z0.z, 1e-10f); v[3] = a.w / fmaxf(z0.w, 1e-10f);
    v[4] = c4.x / fmaxf(z1.x, 1e-10f); v[5] = c4.y / fmaxf(z1.y, 1e-10f);
    v[6] = c4.z / fmaxf(z1.z, 1e-10f); v[7] = c4.w / fmaxf(z1.w, 1e-10f);
    float s = 0.f;
    unsigned char o[8];
    #pragma unroll
    for (int j = 0; j < 8; ++j) { s += v[j]; o[j] = f2fp8(v[j] * 65536.f); }
    uint2 w;
    w.x = (unsigned int)o[0] | ((unsigned int)o[1] << 8) | ((unsigned int)o[2] << 16) | ((unsigned int)o[3] << 24);
    w.y = (unsigned int)o[4] | ((unsigned int)o[5] << 8) | ((unsigned int)o[6] << 16) | ((unsigned int)o[7] << 24);
    ((uint2*)(xs + (size_t)bc * 2048))[t] = w;
    #pragma unroll
    for (int off = 32; off >= 1; off >>= 1) s += __shfl_xor(s, off, 64);
    __shared__ float red[4];
    if ((t & 63) == 0) red[t >> 6] = s;
    __syncthreads();
    if (t == 0) colsum[bc] = red[0] + red[1] + red[2] + red[3];
}

// base[b][d] = bp[d] + sum_c Wp[d,c]*colsum[b][c]  (exact fp32 path)
__global__ __launch_bounds__(256)
void basek(const float* __restrict__ Wp, const float* __restrict__ colsum,
           const float* __restrict__ bp, float* __restrict__ base)
{
    const int d = blockIdx.x, t = threadIdx.x;
    float4 w = *(const float4*)(Wp + (size_t)d * 1024 + t * 4);
    float pb[8];
    #pragma unroll
    for (int b = 0; b < 8; ++b) {
        float4 cs = *(const float4*)(colsum + b * 1024 + t * 4);
        pb[b] = w.x * cs.x + w.y * cs.y + w.z * cs.z + w.w * cs.w;
    }
    __shared__ float red[8][4];
    #pragma unroll
    for (int b = 0; b < 8; ++b) {
        float s = pb[b];
        #pragma unroll
        for (int off = 32; off >= 1; off >>= 1) s += __shfl_xor(s, off, 64);
        if ((t & 63) == 0) red[b][t >> 6] = s;
    }
    __syncthreads();
    if (t < 8) base[t * 1024 + d] = bp[d] + red[t][0] + red[t][1] + red[t][2] + red[t][3];
}

extern "C" void kernel_launch(void* const* d_in, const int* in_sizes, int n_in,
                              void* d_out, int out_size, void* d_ws, size_t ws_size,
                              hipStream_t stream)
{
    const float* x  = (const float*)d_in[0];
    const float* Wk = (const float*)d_in[1];
    const float* bk = (const float*)d_in[2];
    const float* Wq = (const float*)d_in[3];
    const float* bq = (const float*)d_in[4];
    const float* Wp = (const float*)d_in[5];
    const float* bp = (const float*)d_in[6];
    float* out = (float*)d_out;

    const float kscale = 2.0f / 2048.0f;

    // ws layout (xt slot retained for Dlt alias): Dlt 16.8MB (in old xt slot) |
    // KQt bf16 8.4MB | Wkqb bf16 0.5MB | Wp8 1MB | St8 33.5MB | xs8 16.8MB | floats
    bf16* xt   = (bf16*)d_ws;                                // slot reused by Dlt
    bf16* KQt  = xt + (size_t)8 * 2048 * 1024;
    bf16* Wkqb = KQt + (size_t)8 * 2048 * 256;
    unsigned char* Wp8 = (unsigned char*)(Wkqb + (size_t)256 * 1024);
    unsigned char* St8 = Wp8 + (size_t)1048576;              // [b][m][l]
    unsigned char* xs8 = St8 + (size_t)8 * 2048 * 2048;      // [b][c][l]
    float* Z      = (float*)(xs8 + (size_t)8 * 1024 * 2048); // [b][2048]
    float* colsum = Z + 8 * 2048;
    float* base   = colsum + 8 * 1024;
    float* scl    = base + 8 * 1024;
    float* b2     = scl + 256;
    unsigned char* Dlt = (unsigned char*)d_ws;               // [b][m][c]

    dim3 blk(256, 1, 1);
    dim3 blk512(512, 1, 1);

    // weights conv + bias prep + Z zero, one dispatch
    conv_wz<<<dim3(645), blk, 0, stream>>>(Wk, Wq, Wp, Wkqb, Wp8,
                                           bk, bq, scl, b2, Z, kscale);

    // stage 1+2 FUSED with x transpose (dbuf): KQt[l][0:128]=K*kscale, [128:256]=Q
    // grid: 8 bz x 32 mT = 256 blocks; x read once.
    gemm12<<<dim3(256), blk, 0, stream>>>(x, Wkqb, KQt, scl, b2);

    // stage 3 (dedicated 256^2 single-shot): St8[m][l] = fp8((exp(v)-1)*2^12);
    // Z[l] += col sums of exp (exact fp32). grid: 8 x (8x8) = 512 blocks
    gemm_s3<<<dim3(8 * 8 * 8), blk512, 0, stream>>>(
        KQt + 128, 2048L * 256, 256,  KQt, 2048L * 256, 256,
        St8, 2048L * 2048, 2048,  Z);

    normx<<<dim3(8 * 1024), blk, 0, stream>>>(x, Z, xs8, colsum);
    basek<<<dim3(1024), blk, 0, stream>>>(Wp, colsum, bp, base);

    // stage 5 (fp8 MX, 256^2 8-phase): Dlt[m][c] = fp8(acc*2^-10)
    gemm_f8<0, false><<<dim3(8 * 8 * 4), blk512, 0, stream>>>(
        St8, 2048L * 2048, 2048,  xs8, 1024L * 2048, 2048,
        Dlt, 2048L * 1024, 1024,  nullptr, 0.0009765625f, 2048, 2);

    // stage 6 (fp8 MX, 256^2 8-phase): out[d][m] = acc*2^-29 + base[b][d]
    gemm_f8<2, true><<<dim3(8 * 4 * 8), blk512, 0, stream>>>(
        Wp8, 0, 1024,  Dlt, 2048L * 1024, 1024,
        out, 1024L * 2048, 2048,  base, 1.862645149230957e-9f, 1024, 2);
}